// Round 1
// baseline (944.621 us; speedup 1.0000x reference)
//
#include <hip/hip_runtime.h>

#define NEG_SLOPE 0.2f

// ---------------- GEMM1: h1[N,64] = x[N,128] @ W1[128,64] ----------------
__global__ __launch_bounds__(256) void k_gemm1(const float* __restrict__ x,
                                               const float* __restrict__ W,
                                               float* __restrict__ h1, int N) {
  __shared__ float sW[128 * 64];  // 32 KB
  __shared__ float sX[16 * 128];  // 8 KB
  const int t = threadIdx.x;
  // stage W (all of it)
  for (int i = 0; i < 32; ++i) sW[t + i * 256] = W[t + i * 256];
  const int r0 = blockIdx.x * 16;
  // stage 16 rows of x
  for (int i = 0; i < 8; ++i) {
    int idx = t + i * 256;             // 0..2047
    int r = idx >> 7, k = idx & 127;
    int gr = r0 + r;
    sX[idx] = (gr < N) ? x[gr * 128 + k] : 0.f;
  }
  __syncthreads();
  const int col = t & 63;
  const int rg = t >> 6;  // 0..3; rows rg, rg+4, rg+8, rg+12
  float a0 = 0.f, a1 = 0.f, a2 = 0.f, a3 = 0.f;
#pragma unroll 4
  for (int k = 0; k < 128; ++k) {
    float w = sW[k * 64 + col];          // stride-1 across lanes: conflict-free
    a0 += sX[(rg + 0) * 128 + k] * w;    // wave-uniform: broadcast
    a1 += sX[(rg + 4) * 128 + k] * w;
    a2 += sX[(rg + 8) * 128 + k] * w;
    a3 += sX[(rg + 12) * 128 + k] * w;
  }
  if (r0 + rg + 0 < N) h1[(r0 + rg + 0) * 64 + col] = a0;
  if (r0 + rg + 4 < N) h1[(r0 + rg + 4) * 64 + col] = a1;
  if (r0 + rg + 8 < N) h1[(r0 + rg + 8) * 64 + col] = a2;
  if (r0 + rg + 12 < N) h1[(r0 + rg + 12) * 64 + col] = a3;
}

// ---------------- scores layer1: es[N,2], ed[N,2] ----------------
__global__ __launch_bounds__(256) void k_scores1(const float* __restrict__ h1,
                                                 const float* __restrict__ a_src,
                                                 const float* __restrict__ a_dst,
                                                 float* __restrict__ es,
                                                 float* __restrict__ ed, int N) {
  int n = blockIdx.x * blockDim.x + threadIdx.x;
  if (n >= N) return;
  const float4* hp = (const float4*)(h1 + n * 64);
  const float4* as = (const float4*)a_src;
  const float4* ad = (const float4*)a_dst;
  float s[2] = {0.f, 0.f}, d[2] = {0.f, 0.f};
#pragma unroll
  for (int q = 0; q < 16; ++q) {
    float4 v = hp[q];
    float4 a = as[q];
    float4 b = ad[q];
    int hh = q >> 3;
    s[hh] += v.x * a.x + v.y * a.y + v.z * a.z + v.w * a.w;
    d[hh] += v.x * b.x + v.y * b.y + v.z * b.z + v.w * b.w;
  }
  es[n * 2 + 0] = s[0]; es[n * 2 + 1] = s[1];
  ed[n * 2 + 0] = d[0]; ed[n * 2 + 1] = d[1];
}

// ---------------- init accumulators with bias ----------------
__global__ __launch_bounds__(256) void k_init_bias(float* __restrict__ out,
                                                   const float* __restrict__ bias,
                                                   int total, int mask) {
  int i = blockIdx.x * blockDim.x + threadIdx.x;
  if (i < total) out[i] = bias[i & mask];
}

// ---------------- edge weights + denom, layer 1 (2 heads) ----------------
__global__ __launch_bounds__(256) void k_edgew1(const int* __restrict__ srcv,
                                                const int* __restrict__ dstv,
                                                const float* __restrict__ es,
                                                const float* __restrict__ ed,
                                                float* __restrict__ w,
                                                float* __restrict__ denom,
                                                int E, int Etot) {
  int e = blockIdx.x * blockDim.x + threadIdx.x;
  if (e >= Etot) return;
  int s, d;
  if (e < E) { s = srcv[e]; d = dstv[e]; } else { s = e - E; d = s; }
  float2 sv = ((const float2*)es)[s];
  float2 dv = ((const float2*)ed)[d];
  float v0 = sv.x + dv.x; v0 = v0 > 0.f ? v0 : NEG_SLOPE * v0;
  float v1 = sv.y + dv.y; v1 = v1 > 0.f ? v1 : NEG_SLOPE * v1;
  float w0 = expf(v0), w1 = expf(v1);
  w[e * 2 + 0] = w0;
  w[e * 2 + 1] = w1;
  atomicAdd(&denom[d * 2 + 0], w0);
  atomicAdd(&denom[d * 2 + 1], w1);
}

// ---------------- message pass layer 1: wave(64) per edge ----------------
__global__ __launch_bounds__(256) void k_msg1(const int* __restrict__ srcv,
                                              const int* __restrict__ dstv,
                                              const float* __restrict__ h1,
                                              const float* __restrict__ w,
                                              const float* __restrict__ denom,
                                              float* __restrict__ out1,
                                              int E, int Etot) {
  int e = (blockIdx.x * blockDim.x + threadIdx.x) >> 6;
  int lane = threadIdx.x & 63;
  if (e >= Etot) return;
  int s, d;
  if (e < E) { s = srcv[e]; d = dstv[e]; } else { s = e - E; d = s; }
  int hh = lane >> 5;
  float alpha = w[e * 2 + hh] / (denom[d * 2 + hh] + 1e-16f);
  atomicAdd(&out1[d * 64 + lane], h1[s * 64 + lane] * alpha);
}

// ---------------- GEMM2: hL2[N,32] = relu(out1)[N,64] @ W2[64,32] ----------------
__global__ __launch_bounds__(256) void k_gemm2(const float* __restrict__ out1,
                                               const float* __restrict__ W,
                                               float* __restrict__ hL2, int N) {
  __shared__ float sW[64 * 32];  // 8 KB
  __shared__ float sX[32 * 64];  // 8 KB
  const int t = threadIdx.x;
  for (int i = 0; i < 8; ++i) sW[t + i * 256] = W[t + i * 256];
  const int r0 = blockIdx.x * 32;
  for (int i = 0; i < 8; ++i) {
    int idx = t + i * 256;  // 0..2047
    int r = idx >> 6, k = idx & 63;
    int gr = r0 + r;
    float v = (gr < N) ? out1[gr * 64 + k] : 0.f;
    sX[idx] = fmaxf(v, 0.f);  // fused ReLU (bias already in out1)
  }
  __syncthreads();
  const int col = t & 31;
  const int rg = t >> 5;  // 0..7; rows rg + 8j
  float a0 = 0.f, a1 = 0.f, a2 = 0.f, a3 = 0.f;
#pragma unroll 4
  for (int k = 0; k < 64; ++k) {
    float w = sW[k * 32 + col];
    a0 += sX[(rg + 0) * 64 + k] * w;
    a1 += sX[(rg + 8) * 64 + k] * w;
    a2 += sX[(rg + 16) * 64 + k] * w;
    a3 += sX[(rg + 24) * 64 + k] * w;
  }
  if (r0 + rg + 0 < N) hL2[(r0 + rg + 0) * 32 + col] = a0;
  if (r0 + rg + 8 < N) hL2[(r0 + rg + 8) * 32 + col] = a1;
  if (r0 + rg + 16 < N) hL2[(r0 + rg + 16) * 32 + col] = a2;
  if (r0 + rg + 24 < N) hL2[(r0 + rg + 24) * 32 + col] = a3;
}

// ---------------- scores layer2 (1 head) ----------------
__global__ __launch_bounds__(256) void k_scores2(const float* __restrict__ hL2,
                                                 const float* __restrict__ a_src,
                                                 const float* __restrict__ a_dst,
                                                 float* __restrict__ es,
                                                 float* __restrict__ ed, int N) {
  int n = blockIdx.x * blockDim.x + threadIdx.x;
  if (n >= N) return;
  const float4* hp = (const float4*)(hL2 + n * 32);
  const float4* as = (const float4*)a_src;
  const float4* ad = (const float4*)a_dst;
  float s = 0.f, d = 0.f;
#pragma unroll
  for (int q = 0; q < 8; ++q) {
    float4 v = hp[q];
    float4 a = as[q];
    float4 b = ad[q];
    s += v.x * a.x + v.y * a.y + v.z * a.z + v.w * a.w;
    d += v.x * b.x + v.y * b.y + v.z * b.z + v.w * b.w;
  }
  es[n] = s;
  ed[n] = d;
}

// ---------------- edge weights + denom, layer 2 (1 head) ----------------
__global__ __launch_bounds__(256) void k_edgew2(const int* __restrict__ srcv,
                                                const int* __restrict__ dstv,
                                                const float* __restrict__ es,
                                                const float* __restrict__ ed,
                                                float* __restrict__ w,
                                                float* __restrict__ denom,
                                                int E, int Etot) {
  int e = blockIdx.x * blockDim.x + threadIdx.x;
  if (e >= Etot) return;
  int s, d;
  if (e < E) { s = srcv[e]; d = dstv[e]; } else { s = e - E; d = s; }
  float v = es[s] + ed[d];
  v = v > 0.f ? v : NEG_SLOPE * v;
  float ww = expf(v);
  w[e] = ww;
  atomicAdd(&denom[d], ww);
}

// ---------------- message pass layer 2: half-wave(32) per edge ----------------
__global__ __launch_bounds__(256) void k_msg2(const int* __restrict__ srcv,
                                              const int* __restrict__ dstv,
                                              const float* __restrict__ hL2,
                                              const float* __restrict__ w,
                                              const float* __restrict__ denom,
                                              float* __restrict__ out,
                                              int E, int Etot) {
  int e = (blockIdx.x * blockDim.x + threadIdx.x) >> 5;
  int lane = threadIdx.x & 31;
  if (e >= Etot) return;
  int s, d;
  if (e < E) { s = srcv[e]; d = dstv[e]; } else { s = e - E; d = s; }
  float alpha = w[e] / (denom[d] + 1e-16f);
  atomicAdd(&out[d * 32 + lane], hL2[s * 32 + lane] * alpha);
}

extern "C" void kernel_launch(void* const* d_in, const int* in_sizes, int n_in,
                              void* d_out, int out_size, void* d_ws, size_t ws_size,
                              hipStream_t stream) {
  const float* x      = (const float*)d_in[0];
  const int*   ei     = (const int*)d_in[1];
  const float* W1     = (const float*)d_in[2];
  const float* a_src1 = (const float*)d_in[3];
  const float* a_dst1 = (const float*)d_in[4];
  const float* b1     = (const float*)d_in[5];
  const float* W2     = (const float*)d_in[6];
  const float* a_src2 = (const float*)d_in[7];
  const float* a_dst2 = (const float*)d_in[8];
  const float* b2     = (const float*)d_in[9];
  float* out = (float*)d_out;

  const int N = in_sizes[0] / 128;
  const int E = in_sizes[1] / 2;
  const int Etot = E + N;
  const int* srcv = ei;
  const int* dstv = ei + E;

  // workspace carve (floats)
  float* p = (float*)d_ws;
  float* h1     = p; p += (size_t)N * 64;
  float* es1    = p; p += (size_t)N * 2;
  float* ed1    = p; p += (size_t)N * 2;
  float* denom1 = p; p += (size_t)N * 2;
  float* w1     = p; p += (size_t)Etot * 2;
  float* out1   = p; p += (size_t)N * 64;
  float* hL2    = p; p += (size_t)N * 32;
  float* es2    = p; p += (size_t)N;
  float* ed2    = p; p += (size_t)N;
  float* denom2 = p; p += (size_t)N;
  float* w2     = p; p += (size_t)Etot;

  hipMemsetAsync(denom1, 0, (size_t)N * 2 * sizeof(float), stream);
  hipMemsetAsync(denom2, 0, (size_t)N * sizeof(float), stream);

  // ---- layer 1 ----
  k_gemm1<<<(N + 15) / 16, 256, 0, stream>>>(x, W1, h1, N);
  k_scores1<<<(N + 255) / 256, 256, 0, stream>>>(h1, a_src1, a_dst1, es1, ed1, N);
  k_init_bias<<<((size_t)N * 64 + 255) / 256, 256, 0, stream>>>(out1, b1, N * 64, 63);
  k_edgew1<<<(Etot + 255) / 256, 256, 0, stream>>>(srcv, dstv, es1, ed1, w1, denom1, E, Etot);
  k_msg1<<<(Etot + 3) / 4, 256, 0, stream>>>(srcv, dstv, h1, w1, denom1, out1, E, Etot);

  // ---- layer 2 ----
  k_gemm2<<<(N + 31) / 32, 256, 0, stream>>>(out1, W2, hL2, N);
  k_scores2<<<(N + 255) / 256, 256, 0, stream>>>(hL2, a_src2, a_dst2, es2, ed2, N);
  k_init_bias<<<((size_t)N * 32 + 255) / 256, 256, 0, stream>>>(out, b2, N * 32, 31);
  k_edgew2<<<(Etot + 255) / 256, 256, 0, stream>>>(srcv, dstv, es2, ed2, w2, denom2, E, Etot);
  k_msg2<<<(Etot + 7) / 8, 256, 0, stream>>>(srcv, dstv, hL2, w2, denom2, out, E, Etot);
}

// Round 2
// 686.784 us; speedup vs baseline: 1.3754x; 1.3754x over previous
//
#include <hip/hip_runtime.h>

#define NEG_SLOPE 0.2f

// ============ CSR build (dst-sorted, self-loops handled implicitly) ============

__global__ __launch_bounds__(256) void k_hist(const int* __restrict__ dstv,
                                              int* __restrict__ cnt, int E) {
  int e = blockIdx.x * blockDim.x + threadIdx.x;
  if (e < E) atomicAdd(&cnt[dstv[e]], 1);
}

// single-block exclusive scan over N counts -> rowptr[N+1], cursor copy
__global__ __launch_bounds__(1024) void k_scan(const int* __restrict__ cnt,
                                               int* __restrict__ rowptr,
                                               int* __restrict__ cursor, int N) {
  __shared__ int part[1024];
  int t = threadIdx.x;
  int chunk = (N + 1023) >> 10;
  int b = t * chunk;
  int sum = 0;
  for (int i = 0; i < chunk; ++i) {
    int idx = b + i;
    if (idx < N) sum += cnt[idx];
  }
  part[t] = sum;
  __syncthreads();
  for (int off = 1; off < 1024; off <<= 1) {
    int v = (t >= off) ? part[t - off] : 0;
    __syncthreads();
    part[t] += v;
    __syncthreads();
  }
  int excl = (t == 0) ? 0 : part[t - 1];
  for (int i = 0; i < chunk; ++i) {
    int idx = b + i;
    if (idx < N) {
      rowptr[idx] = excl;
      cursor[idx] = excl;
      excl += cnt[idx];
    }
  }
  if (t == 0) rowptr[N] = part[1023];
}

__global__ __launch_bounds__(256) void k_scatter(const int* __restrict__ srcv,
                                                 const int* __restrict__ dstv,
                                                 int* __restrict__ cursor,
                                                 int* __restrict__ col, int E) {
  int e = blockIdx.x * blockDim.x + threadIdx.x;
  if (e >= E) return;
  int pos = atomicAdd(&cursor[dstv[e]], 1);
  col[pos] = srcv[e];
}

// ---------------- GEMM1: h1[N,64] = x[N,128] @ W1[128,64] ----------------
__global__ __launch_bounds__(256) void k_gemm1(const float* __restrict__ x,
                                               const float* __restrict__ W,
                                               float* __restrict__ h1, int N) {
  __shared__ float sW[128 * 64];
  __shared__ float sX[16 * 128];
  const int t = threadIdx.x;
  for (int i = 0; i < 32; ++i) sW[t + i * 256] = W[t + i * 256];
  const int r0 = blockIdx.x * 16;
  for (int i = 0; i < 8; ++i) {
    int idx = t + i * 256;
    int r = idx >> 7, k = idx & 127;
    int gr = r0 + r;
    sX[idx] = (gr < N) ? x[gr * 128 + k] : 0.f;
  }
  __syncthreads();
  const int col = t & 63;
  const int rg = t >> 6;
  float a0 = 0.f, a1 = 0.f, a2 = 0.f, a3 = 0.f;
#pragma unroll 4
  for (int k = 0; k < 128; ++k) {
    float w = sW[k * 64 + col];
    a0 += sX[(rg + 0) * 128 + k] * w;
    a1 += sX[(rg + 4) * 128 + k] * w;
    a2 += sX[(rg + 8) * 128 + k] * w;
    a3 += sX[(rg + 12) * 128 + k] * w;
  }
  if (r0 + rg + 0 < N) h1[(r0 + rg + 0) * 64 + col] = a0;
  if (r0 + rg + 4 < N) h1[(r0 + rg + 4) * 64 + col] = a1;
  if (r0 + rg + 8 < N) h1[(r0 + rg + 8) * 64 + col] = a2;
  if (r0 + rg + 12 < N) h1[(r0 + rg + 12) * 64 + col] = a3;
}

// ---------------- scores layer1: es[N,2], ed[N,2] ----------------
__global__ __launch_bounds__(256) void k_scores1(const float* __restrict__ h1,
                                                 const float* __restrict__ a_src,
                                                 const float* __restrict__ a_dst,
                                                 float* __restrict__ es,
                                                 float* __restrict__ ed, int N) {
  int n = blockIdx.x * blockDim.x + threadIdx.x;
  if (n >= N) return;
  const float4* hp = (const float4*)(h1 + n * 64);
  const float4* as = (const float4*)a_src;
  const float4* ad = (const float4*)a_dst;
  float s[2] = {0.f, 0.f}, d[2] = {0.f, 0.f};
#pragma unroll
  for (int q = 0; q < 16; ++q) {
    float4 v = hp[q];
    float4 a = as[q];
    float4 b = ad[q];
    int hh = q >> 3;
    s[hh] += v.x * a.x + v.y * a.y + v.z * a.z + v.w * a.w;
    d[hh] += v.x * b.x + v.y * b.y + v.z * b.z + v.w * b.w;
  }
  es[n * 2 + 0] = s[0]; es[n * 2 + 1] = s[1];
  ed[n * 2 + 0] = d[0]; ed[n * 2 + 1] = d[1];
}

// -------- fused softmax+aggregate layer 1: one wave(64) per dst node --------
__global__ __launch_bounds__(256) void k_agg1(const int* __restrict__ rowptr,
                                              const int* __restrict__ col,
                                              const float* __restrict__ h1,
                                              const float* __restrict__ es,
                                              const float* __restrict__ ed,
                                              const float* __restrict__ bias,
                                              float* __restrict__ out1, int N) {
  int d = (blockIdx.x * blockDim.x + threadIdx.x) >> 6;
  int lane = threadIdx.x & 63;
  if (d >= N) return;
  int hh = lane >> 5;
  float edv = ed[d * 2 + hh];
  // self-loop (src = d)
  float v = es[d * 2 + hh] + edv;
  v = v > 0.f ? v : NEG_SLOPE * v;
  float w = __expf(v);
  float acc = w * h1[d * 64 + lane];
  float wsum = w;
  int beg = rowptr[d], end = rowptr[d + 1];
  for (int j = beg; j < end; ++j) {
    int s = col[j];
    float vv = es[s * 2 + hh] + edv;
    vv = vv > 0.f ? vv : NEG_SLOPE * vv;
    float ww = __expf(vv);
    acc += ww * h1[s * 64 + lane];
    wsum += ww;
  }
  out1[d * 64 + lane] = acc / (wsum + 1e-16f) + bias[lane];
}

// ---------------- GEMM2: hL2[N,32] = relu(out1)[N,64] @ W2[64,32] ----------------
__global__ __launch_bounds__(256) void k_gemm2(const float* __restrict__ out1,
                                               const float* __restrict__ W,
                                               float* __restrict__ hL2, int N) {
  __shared__ float sW[64 * 32];
  __shared__ float sX[32 * 64];
  const int t = threadIdx.x;
  for (int i = 0; i < 8; ++i) sW[t + i * 256] = W[t + i * 256];
  const int r0 = blockIdx.x * 32;
  for (int i = 0; i < 8; ++i) {
    int idx = t + i * 256;
    int r = idx >> 6, k = idx & 63;
    int gr = r0 + r;
    float v = (gr < N) ? out1[gr * 64 + k] : 0.f;
    sX[idx] = fmaxf(v, 0.f);  // fused ReLU
  }
  __syncthreads();
  const int col = t & 31;
  const int rg = t >> 5;
  float a0 = 0.f, a1 = 0.f, a2 = 0.f, a3 = 0.f;
#pragma unroll 4
  for (int k = 0; k < 64; ++k) {
    float w = sW[k * 32 + col];
    a0 += sX[(rg + 0) * 64 + k] * w;
    a1 += sX[(rg + 8) * 64 + k] * w;
    a2 += sX[(rg + 16) * 64 + k] * w;
    a3 += sX[(rg + 24) * 64 + k] * w;
  }
  if (r0 + rg + 0 < N) hL2[(r0 + rg + 0) * 32 + col] = a0;
  if (r0 + rg + 8 < N) hL2[(r0 + rg + 8) * 32 + col] = a1;
  if (r0 + rg + 16 < N) hL2[(r0 + rg + 16) * 32 + col] = a2;
  if (r0 + rg + 24 < N) hL2[(r0 + rg + 24) * 32 + col] = a3;
}

// ---------------- scores layer2 (1 head) ----------------
__global__ __launch_bounds__(256) void k_scores2(const float* __restrict__ hL2,
                                                 const float* __restrict__ a_src,
                                                 const float* __restrict__ a_dst,
                                                 float* __restrict__ es,
                                                 float* __restrict__ ed, int N) {
  int n = blockIdx.x * blockDim.x + threadIdx.x;
  if (n >= N) return;
  const float4* hp = (const float4*)(hL2 + n * 32);
  const float4* as = (const float4*)a_src;
  const float4* ad = (const float4*)a_dst;
  float s = 0.f, d = 0.f;
#pragma unroll
  for (int q = 0; q < 8; ++q) {
    float4 v = hp[q];
    float4 a = as[q];
    float4 b = ad[q];
    s += v.x * a.x + v.y * a.y + v.z * a.z + v.w * a.w;
    d += v.x * b.x + v.y * b.y + v.z * b.z + v.w * b.w;
  }
  es[n] = s;
  ed[n] = d;
}

// -------- fused softmax+aggregate layer 2: half-wave(32) per dst node --------
__global__ __launch_bounds__(256) void k_agg2(const int* __restrict__ rowptr,
                                              const int* __restrict__ col,
                                              const float* __restrict__ hL2,
                                              const float* __restrict__ es,
                                              const float* __restrict__ ed,
                                              const float* __restrict__ bias,
                                              float* __restrict__ out, int N) {
  int d = (blockIdx.x * blockDim.x + threadIdx.x) >> 5;
  int lane = threadIdx.x & 31;
  if (d >= N) return;
  float edv = ed[d];
  float v = es[d] + edv;
  v = v > 0.f ? v : NEG_SLOPE * v;
  float w = __expf(v);
  float acc = w * hL2[d * 32 + lane];
  float wsum = w;
  int beg = rowptr[d], end = rowptr[d + 1];
  for (int j = beg; j < end; ++j) {
    int s = col[j];
    float vv = es[s] + edv;
    vv = vv > 0.f ? vv : NEG_SLOPE * vv;
    float ww = __expf(vv);
    acc += ww * hL2[s * 32 + lane];
    wsum += ww;
  }
  out[d * 32 + lane] = acc / (wsum + 1e-16f) + bias[lane];
}

extern "C" void kernel_launch(void* const* d_in, const int* in_sizes, int n_in,
                              void* d_out, int out_size, void* d_ws, size_t ws_size,
                              hipStream_t stream) {
  const float* x      = (const float*)d_in[0];
  const int*   ei     = (const int*)d_in[1];
  const float* W1     = (const float*)d_in[2];
  const float* a_src1 = (const float*)d_in[3];
  const float* a_dst1 = (const float*)d_in[4];
  const float* b1     = (const float*)d_in[5];
  const float* W2     = (const float*)d_in[6];
  const float* a_src2 = (const float*)d_in[7];
  const float* a_dst2 = (const float*)d_in[8];
  const float* b2     = (const float*)d_in[9];
  float* out = (float*)d_out;

  const int N = in_sizes[0] / 128;
  const int E = in_sizes[1] / 2;
  const int* srcv = ei;
  const int* dstv = ei + E;

  // workspace carve (16B aligned chunks)
  char* base = (char*)d_ws;
  size_t off = 0;
  auto carve = [&](size_t bytes) {
    void* p = base + off;
    off += (bytes + 15) & ~(size_t)15;
    return p;
  };
  float* h1     = (float*)carve((size_t)N * 64 * 4);
  float* es1    = (float*)carve((size_t)N * 2 * 4);
  float* ed1    = (float*)carve((size_t)N * 2 * 4);
  float* out1   = (float*)carve((size_t)N * 64 * 4);
  float* hL2    = (float*)carve((size_t)N * 32 * 4);
  float* es2    = (float*)carve((size_t)N * 4);
  float* ed2    = (float*)carve((size_t)N * 4);
  int*   cnt    = (int*)carve((size_t)N * 4);
  int*   rowptr = (int*)carve((size_t)(N + 1) * 4);
  int*   cursor = (int*)carve((size_t)N * 4);
  int*   col    = (int*)carve((size_t)E * 4);

  // ---- CSR build (shared by both layers) ----
  hipMemsetAsync(cnt, 0, (size_t)N * sizeof(int), stream);
  k_hist<<<(E + 255) / 256, 256, 0, stream>>>(dstv, cnt, E);
  k_scan<<<1, 1024, 0, stream>>>(cnt, rowptr, cursor, N);
  k_scatter<<<(E + 255) / 256, 256, 0, stream>>>(srcv, dstv, cursor, col, E);

  // ---- layer 1 ----
  k_gemm1<<<(N + 15) / 16, 256, 0, stream>>>(x, W1, h1, N);
  k_scores1<<<(N + 255) / 256, 256, 0, stream>>>(h1, a_src1, a_dst1, es1, ed1, N);
  k_agg1<<<((size_t)N * 64 + 255) / 256, 256, 0, stream>>>(rowptr, col, h1, es1, ed1, b1, out1, N);

  // ---- layer 2 ----
  k_gemm2<<<(N + 31) / 32, 256, 0, stream>>>(out1, W2, hL2, N);
  k_scores2<<<(N + 255) / 256, 256, 0, stream>>>(hL2, a_src2, a_dst2, es2, ed2, N);
  k_agg2<<<((size_t)N * 32 + 255) / 256, 256, 0, stream>>>(rowptr, col, hL2, es2, ed2, b2, out, N);
}

// Round 3
// 531.372 us; speedup vs baseline: 1.7777x; 1.2925x over previous
//
#include <hip/hip_runtime.h>

#define NEG_SLOPE 0.2f

// ============ CSR build (dst-sorted, self-loops handled implicitly) ============

__global__ __launch_bounds__(256) void k_hist(const int* __restrict__ dstv,
                                              int* __restrict__ cnt, int E) {
  int e = blockIdx.x * blockDim.x + threadIdx.x;
  if (e < E) atomicAdd(&cnt[dstv[e]], 1);
}

// single-block exclusive scan over N counts -> rowptr[N+1], cursor copy
__global__ __launch_bounds__(1024) void k_scan(const int* __restrict__ cnt,
                                               int* __restrict__ rowptr,
                                               int* __restrict__ cursor, int N) {
  __shared__ int part[1024];
  int t = threadIdx.x;
  int chunk = (N + 1023) >> 10;
  int b = t * chunk;
  int sum = 0;
  for (int i = 0; i < chunk; ++i) {
    int idx = b + i;
    if (idx < N) sum += cnt[idx];
  }
  part[t] = sum;
  __syncthreads();
  for (int off = 1; off < 1024; off <<= 1) {
    int v = (t >= off) ? part[t - off] : 0;
    __syncthreads();
    part[t] += v;
    __syncthreads();
  }
  int excl = (t == 0) ? 0 : part[t - 1];
  for (int i = 0; i < chunk; ++i) {
    int idx = b + i;
    if (idx < N) {
      rowptr[idx] = excl;
      cursor[idx] = excl;
      excl += cnt[idx];
    }
  }
  if (t == 0) rowptr[N] = part[1023];
}

__global__ __launch_bounds__(256) void k_scatter(const int* __restrict__ srcv,
                                                 const int* __restrict__ dstv,
                                                 int* __restrict__ cursor,
                                                 int* __restrict__ col, int E) {
  int e = blockIdx.x * blockDim.x + threadIdx.x;
  if (e >= E) return;
  int pos = atomicAdd(&cursor[dstv[e]], 1);
  col[pos] = srcv[e];
}

// ---------------- GEMM1: h1[N,64] = x[N,128] @ W1[128,64] ----------------
__global__ __launch_bounds__(256) void k_gemm1(const float* __restrict__ x,
                                               const float* __restrict__ W,
                                               float* __restrict__ h1, int N) {
  __shared__ float sW[128 * 64];
  __shared__ float sX[16 * 128];
  const int t = threadIdx.x;
  for (int i = 0; i < 32; ++i) sW[t + i * 256] = W[t + i * 256];
  const int r0 = blockIdx.x * 16;
  for (int i = 0; i < 8; ++i) {
    int idx = t + i * 256;
    int r = idx >> 7, k = idx & 127;
    int gr = r0 + r;
    sX[idx] = (gr < N) ? x[gr * 128 + k] : 0.f;
  }
  __syncthreads();
  const int col = t & 63;
  const int rg = t >> 6;
  float a0 = 0.f, a1 = 0.f, a2 = 0.f, a3 = 0.f;
#pragma unroll 4
  for (int k = 0; k < 128; ++k) {
    float w = sW[k * 64 + col];
    a0 += sX[(rg + 0) * 128 + k] * w;
    a1 += sX[(rg + 4) * 128 + k] * w;
    a2 += sX[(rg + 8) * 128 + k] * w;
    a3 += sX[(rg + 12) * 128 + k] * w;
  }
  if (r0 + rg + 0 < N) h1[(r0 + rg + 0) * 64 + col] = a0;
  if (r0 + rg + 4 < N) h1[(r0 + rg + 4) * 64 + col] = a1;
  if (r0 + rg + 8 < N) h1[(r0 + rg + 8) * 64 + col] = a2;
  if (r0 + rg + 12 < N) h1[(r0 + rg + 12) * 64 + col] = a3;
}

// ---------------- scores layer1: es[N,2], ed[N,2] ----------------
__global__ __launch_bounds__(256) void k_scores1(const float* __restrict__ h1,
                                                 const float* __restrict__ a_src,
                                                 const float* __restrict__ a_dst,
                                                 float* __restrict__ es,
                                                 float* __restrict__ ed, int N) {
  int n = blockIdx.x * blockDim.x + threadIdx.x;
  if (n >= N) return;
  const float4* hp = (const float4*)(h1 + n * 64);
  const float4* as = (const float4*)a_src;
  const float4* ad = (const float4*)a_dst;
  float s[2] = {0.f, 0.f}, d[2] = {0.f, 0.f};
#pragma unroll
  for (int q = 0; q < 16; ++q) {
    float4 v = hp[q];
    float4 a = as[q];
    float4 b = ad[q];
    int hh = q >> 3;
    s[hh] += v.x * a.x + v.y * a.y + v.z * a.z + v.w * a.w;
    d[hh] += v.x * b.x + v.y * b.y + v.z * b.z + v.w * b.w;
  }
  es[n * 2 + 0] = s[0]; es[n * 2 + 1] = s[1];
  ed[n * 2 + 0] = d[0]; ed[n * 2 + 1] = d[1];
}

// -------- fused softmax+aggregate layer 1: one wave per dst node --------
// 4 lane-groups of 16; group g handles edges beg+g, beg+g+4, ...
// Each group's 16 lanes cover all 64 channels via float4.
__global__ __launch_bounds__(256) void k_agg1(const int* __restrict__ rowptr,
                                              const int* __restrict__ col,
                                              const float* __restrict__ h1,
                                              const float* __restrict__ es,
                                              const float* __restrict__ ed,
                                              const float* __restrict__ bias,
                                              float* __restrict__ out1, int N) {
  int d = (blockIdx.x * blockDim.x + threadIdx.x) >> 6;
  int lane = threadIdx.x & 63;
  if (d >= N) return;
  int g = lane >> 4;        // edge group 0..3
  int q = lane & 15;        // channel quad 0..15
  int ch = q * 4;           // base channel
  int hh = ch >> 5;         // head
  float edv = ed[d * 2 + hh];

  float4 acc = make_float4(0.f, 0.f, 0.f, 0.f);
  float wsum = 0.f;

  // self-loop: group 0 only
  if (g == 0) {
    float v = es[d * 2 + hh] + edv;
    v = v > 0.f ? v : NEG_SLOPE * v;
    float w = __expf(v);
    float4 hv = *(const float4*)(h1 + (size_t)d * 64 + ch);
    acc.x = w * hv.x; acc.y = w * hv.y; acc.z = w * hv.z; acc.w = w * hv.w;
    wsum = w;
  }

  int beg = rowptr[d], end = rowptr[d + 1];
#pragma unroll 2
  for (int j = beg + g; j < end; j += 4) {
    int s = col[j];
    float vv = es[s * 2 + hh] + edv;
    vv = vv > 0.f ? vv : NEG_SLOPE * vv;
    float w = __expf(vv);
    float4 hv = *(const float4*)(h1 + (size_t)s * 64 + ch);
    acc.x += w * hv.x; acc.y += w * hv.y; acc.z += w * hv.z; acc.w += w * hv.w;
    wsum += w;
  }

  // reduce across the 4 groups (lanes with equal q): xor 16, 32
#pragma unroll
  for (int off = 16; off <= 32; off <<= 1) {
    acc.x += __shfl_xor(acc.x, off);
    acc.y += __shfl_xor(acc.y, off);
    acc.z += __shfl_xor(acc.z, off);
    acc.w += __shfl_xor(acc.w, off);
    wsum  += __shfl_xor(wsum, off);
  }

  if (g == 0) {
    float inv = 1.f / (wsum + 1e-16f);
    const float4 bv = *(const float4*)(bias + ch);
    float4 o;
    o.x = acc.x * inv + bv.x;
    o.y = acc.y * inv + bv.y;
    o.z = acc.z * inv + bv.z;
    o.w = acc.w * inv + bv.w;
    *(float4*)(out1 + (size_t)d * 64 + ch) = o;
  }
}

// ---------------- GEMM2: hL2[N,32] = relu(out1)[N,64] @ W2[64,32] ----------------
__global__ __launch_bounds__(256) void k_gemm2(const float* __restrict__ out1,
                                               const float* __restrict__ W,
                                               float* __restrict__ hL2, int N) {
  __shared__ float sW[64 * 32];
  __shared__ float sX[32 * 64];
  const int t = threadIdx.x;
  for (int i = 0; i < 8; ++i) sW[t + i * 256] = W[t + i * 256];
  const int r0 = blockIdx.x * 32;
  for (int i = 0; i < 8; ++i) {
    int idx = t + i * 256;
    int r = idx >> 6, k = idx & 63;
    int gr = r0 + r;
    float v = (gr < N) ? out1[gr * 64 + k] : 0.f;
    sX[idx] = fmaxf(v, 0.f);  // fused ReLU
  }
  __syncthreads();
  const int col = t & 31;
  const int rg = t >> 5;
  float a0 = 0.f, a1 = 0.f, a2 = 0.f, a3 = 0.f;
#pragma unroll 4
  for (int k = 0; k < 64; ++k) {
    float w = sW[k * 32 + col];
    a0 += sX[(rg + 0) * 64 + k] * w;
    a1 += sX[(rg + 8) * 64 + k] * w;
    a2 += sX[(rg + 16) * 64 + k] * w;
    a3 += sX[(rg + 24) * 64 + k] * w;
  }
  if (r0 + rg + 0 < N) hL2[(r0 + rg + 0) * 32 + col] = a0;
  if (r0 + rg + 8 < N) hL2[(r0 + rg + 8) * 32 + col] = a1;
  if (r0 + rg + 16 < N) hL2[(r0 + rg + 16) * 32 + col] = a2;
  if (r0 + rg + 24 < N) hL2[(r0 + rg + 24) * 32 + col] = a3;
}

// ---------------- scores layer2 (1 head) ----------------
__global__ __launch_bounds__(256) void k_scores2(const float* __restrict__ hL2,
                                                 const float* __restrict__ a_src,
                                                 const float* __restrict__ a_dst,
                                                 float* __restrict__ es,
                                                 float* __restrict__ ed, int N) {
  int n = blockIdx.x * blockDim.x + threadIdx.x;
  if (n >= N) return;
  const float4* hp = (const float4*)(hL2 + n * 32);
  const float4* as = (const float4*)a_src;
  const float4* ad = (const float4*)a_dst;
  float s = 0.f, d = 0.f;
#pragma unroll
  for (int q = 0; q < 8; ++q) {
    float4 v = hp[q];
    float4 a = as[q];
    float4 b = ad[q];
    s += v.x * a.x + v.y * a.y + v.z * a.z + v.w * a.w;
    d += v.x * b.x + v.y * b.y + v.z * b.z + v.w * b.w;
  }
  es[n] = s;
  ed[n] = d;
}

// -------- fused softmax+aggregate layer 2: one wave per dst node --------
// 8 lane-groups of 8; group g handles edges beg+g, beg+g+8, ...
__global__ __launch_bounds__(256) void k_agg2(const int* __restrict__ rowptr,
                                              const int* __restrict__ col,
                                              const float* __restrict__ hL2,
                                              const float* __restrict__ es,
                                              const float* __restrict__ ed,
                                              const float* __restrict__ bias,
                                              float* __restrict__ out, int N) {
  int d = (blockIdx.x * blockDim.x + threadIdx.x) >> 6;
  int lane = threadIdx.x & 63;
  if (d >= N) return;
  int g = lane >> 3;       // edge group 0..7
  int q = lane & 7;        // channel quad 0..7
  int ch = q * 4;
  float edv = ed[d];

  float4 acc = make_float4(0.f, 0.f, 0.f, 0.f);
  float wsum = 0.f;

  if (g == 0) {
    float v = es[d] + edv;
    v = v > 0.f ? v : NEG_SLOPE * v;
    float w = __expf(v);
    float4 hv = *(const float4*)(hL2 + (size_t)d * 32 + ch);
    acc.x = w * hv.x; acc.y = w * hv.y; acc.z = w * hv.z; acc.w = w * hv.w;
    wsum = w;
  }

  int beg = rowptr[d], end = rowptr[d + 1];
#pragma unroll 2
  for (int j = beg + g; j < end; j += 8) {
    int s = col[j];
    float vv = es[s] + edv;
    vv = vv > 0.f ? vv : NEG_SLOPE * vv;
    float w = __expf(vv);
    float4 hv = *(const float4*)(hL2 + (size_t)s * 32 + ch);
    acc.x += w * hv.x; acc.y += w * hv.y; acc.z += w * hv.z; acc.w += w * hv.w;
    wsum += w;
  }

  // reduce across the 8 groups (lanes with equal q): xor 8, 16, 32
#pragma unroll
  for (int off = 8; off <= 32; off <<= 1) {
    acc.x += __shfl_xor(acc.x, off);
    acc.y += __shfl_xor(acc.y, off);
    acc.z += __shfl_xor(acc.z, off);
    acc.w += __shfl_xor(acc.w, off);
    wsum  += __shfl_xor(wsum, off);
  }

  if (g == 0) {
    float inv = 1.f / (wsum + 1e-16f);
    const float4 bv = *(const float4*)(bias + ch);
    float4 o;
    o.x = acc.x * inv + bv.x;
    o.y = acc.y * inv + bv.y;
    o.z = acc.z * inv + bv.z;
    o.w = acc.w * inv + bv.w;
    *(float4*)(out + (size_t)d * 32 + ch) = o;
  }
}

extern "C" void kernel_launch(void* const* d_in, const int* in_sizes, int n_in,
                              void* d_out, int out_size, void* d_ws, size_t ws_size,
                              hipStream_t stream) {
  const float* x      = (const float*)d_in[0];
  const int*   ei     = (const int*)d_in[1];
  const float* W1     = (const float*)d_in[2];
  const float* a_src1 = (const float*)d_in[3];
  const float* a_dst1 = (const float*)d_in[4];
  const float* b1     = (const float*)d_in[5];
  const float* W2     = (const float*)d_in[6];
  const float* a_src2 = (const float*)d_in[7];
  const float* a_dst2 = (const float*)d_in[8];
  const float* b2     = (const float*)d_in[9];
  float* out = (float*)d_out;

  const int N = in_sizes[0] / 128;
  const int E = in_sizes[1] / 2;
  const int* srcv = ei;
  const int* dstv = ei + E;

  // workspace carve (16B aligned chunks)
  char* base = (char*)d_ws;
  size_t off = 0;
  auto carve = [&](size_t bytes) {
    void* p = base + off;
    off += (bytes + 15) & ~(size_t)15;
    return p;
  };
  float* h1     = (float*)carve((size_t)N * 64 * 4);
  float* es1    = (float*)carve((size_t)N * 2 * 4);
  float* ed1    = (float*)carve((size_t)N * 2 * 4);
  float* out1   = (float*)carve((size_t)N * 64 * 4);
  float* hL2    = (float*)carve((size_t)N * 32 * 4);
  float* es2    = (float*)carve((size_t)N * 4);
  float* ed2    = (float*)carve((size_t)N * 4);
  int*   cnt    = (int*)carve((size_t)N * 4);
  int*   rowptr = (int*)carve((size_t)(N + 1) * 4);
  int*   cursor = (int*)carve((size_t)N * 4);
  int*   col    = (int*)carve((size_t)E * 4);

  // ---- CSR build (shared by both layers) ----
  hipMemsetAsync(cnt, 0, (size_t)N * sizeof(int), stream);
  k_hist<<<(E + 255) / 256, 256, 0, stream>>>(dstv, cnt, E);
  k_scan<<<1, 1024, 0, stream>>>(cnt, rowptr, cursor, N);
  k_scatter<<<(E + 255) / 256, 256, 0, stream>>>(srcv, dstv, cursor, col, E);

  // ---- layer 1 ----
  k_gemm1<<<(N + 15) / 16, 256, 0, stream>>>(x, W1, h1, N);
  k_scores1<<<(N + 255) / 256, 256, 0, stream>>>(h1, a_src1, a_dst1, es1, ed1, N);
  k_agg1<<<((size_t)N * 64 + 255) / 256, 256, 0, stream>>>(rowptr, col, h1, es1, ed1, b1, out1, N);

  // ---- layer 2 ----
  k_gemm2<<<(N + 31) / 32, 256, 0, stream>>>(out1, W2, hL2, N);
  k_scores2<<<(N + 255) / 256, 256, 0, stream>>>(hL2, a_src2, a_dst2, es2, ed2, N);
  k_agg2<<<((size_t)N * 64 + 255) / 256, 256, 0, stream>>>(rowptr, col, hL2, es2, ed2, b2, out, N);
}

// Round 4
// 273.938 us; speedup vs baseline: 3.4483x; 1.9398x over previous
//
#include <hip/hip_runtime.h>

#define NEG_SLOPE 0.2f
#define DB 128      // dst nodes per bucket
#define NB_MAX 512  // max buckets (N <= 65536)
#define EPB 4096    // edges per block in partition kernels

// ============ CSR build: two-phase LDS-binned counting sort ============

// Phase 0: per-bucket totals
__global__ __launch_bounds__(256) void k_bhist(const int* __restrict__ dstv,
                                               int* __restrict__ bcnt, int E) {
  __shared__ int sh[NB_MAX];
  int t = threadIdx.x;
  sh[t] = 0; sh[t + 256] = 0;
  __syncthreads();
  int base = blockIdx.x * EPB;
#pragma unroll
  for (int i = 0; i < 16; ++i) {
    int e = base + i * 256 + t;
    if (e < E) atomicAdd(&sh[dstv[e] >> 7], 1);
  }
  __syncthreads();
#pragma unroll
  for (int i = 0; i < 2; ++i) {
    int b = t + 256 * i;
    int c = sh[b];
    if (c) atomicAdd(&bcnt[b], c);
  }
}

// Phase 0b: scan bucket totals -> gbase[NB+1], gcur copy; also rowptr[N]=E
__global__ __launch_bounds__(NB_MAX) void k_bscan(const int* __restrict__ bcnt,
                                                  int* __restrict__ gbase,
                                                  int* __restrict__ gcur,
                                                  int* __restrict__ rowptr,
                                                  int NB, int N) {
  __shared__ int s[NB_MAX];
  int t = threadIdx.x;
  int v = (t < NB) ? bcnt[t] : 0;
  s[t] = v;
  __syncthreads();
  for (int off = 1; off < NB_MAX; off <<= 1) {
    int u = (t >= off) ? s[t - off] : 0;
    __syncthreads();
    s[t] += u;
    __syncthreads();
  }
  int excl = s[t] - v;
  if (t < NB) { gbase[t] = excl; gcur[t] = excl; }
  if (t == NB - 1) { gbase[NB] = s[t]; rowptr[N] = s[t]; }
}

// Phase 1: partition edges into bucket segments of ebuf, packed (dlow<<16)|src
__global__ __launch_bounds__(256) void k_part(const int* __restrict__ srcv,
                                              const int* __restrict__ dstv,
                                              int* __restrict__ gcur,
                                              int* __restrict__ ebuf, int E) {
  __shared__ int sh[NB_MAX];
  __shared__ int lbase[NB_MAX];
  int t = threadIdx.x;
  sh[t] = 0; sh[t + 256] = 0;
  __syncthreads();
  int base = blockIdx.x * EPB;
  int dd[16];
#pragma unroll
  for (int i = 0; i < 16; ++i) {
    int e = base + i * 256 + t;
    dd[i] = (e < E) ? dstv[e] : -1;
    if (dd[i] >= 0) atomicAdd(&sh[dd[i] >> 7], 1);
  }
  __syncthreads();
#pragma unroll
  for (int i = 0; i < 2; ++i) {
    int b = t + 256 * i;
    int c = sh[b];
    lbase[b] = c ? atomicAdd(&gcur[b], c) : 0;
    sh[b] = 0;  // becomes local cursor
  }
  __syncthreads();
#pragma unroll
  for (int i = 0; i < 16; ++i) {
    if (dd[i] >= 0) {
      int e = base + i * 256 + t;
      int b = dd[i] >> 7;
      int r = atomicAdd(&sh[b], 1);
      ebuf[lbase[b] + r] = srcv[e] | ((dd[i] & 127) << 16);
    }
  }
}

// Phase 2: per-bucket local counting sort -> rowptr + col (contiguous writes)
__global__ __launch_bounds__(256) void k_csr(const int* __restrict__ gbase,
                                             const int* __restrict__ ebuf,
                                             int* __restrict__ rowptr,
                                             int* __restrict__ col, int N) {
  int b = blockIdx.x;
  int base = gbase[b];
  int cnt = gbase[b + 1] - base;
  int dbase = b * DB;
  __shared__ int dh[DB];
  __shared__ int sc[DB];
  int t = threadIdx.x;
  if (t < DB) dh[t] = 0;
  __syncthreads();
  for (int j = t; j < cnt; j += 256) {
    int p = ebuf[base + j];
    atomicAdd(&dh[p >> 16], 1);
  }
  __syncthreads();
  int v = 0;
  if (t < DB) { v = dh[t]; sc[t] = v; }
  __syncthreads();
  for (int off = 1; off < DB; off <<= 1) {
    int u = 0;
    if (t < DB && t >= off) u = sc[t - off];
    __syncthreads();
    if (t < DB) sc[t] += u;
    __syncthreads();
  }
  if (t < DB) {
    int excl = sc[t] - v;
    int d = dbase + t;
    if (d < N) rowptr[d] = base + excl;
    dh[t] = base + excl;  // global cursor for this dst
  }
  __syncthreads();
  for (int j = t; j < cnt; j += 256) {
    int p = ebuf[base + j];
    int r = atomicAdd(&dh[p >> 16], 1);
    col[r] = p & 0xFFFF;
  }
}

// ---------------- GEMM1: h1[N,64] = x[N,128] @ W1[128,64] ----------------
__global__ __launch_bounds__(256) void k_gemm1(const float* __restrict__ x,
                                               const float* __restrict__ W,
                                               float* __restrict__ h1, int N) {
  __shared__ float sW[128 * 64];
  __shared__ float sX[16 * 128];
  const int t = threadIdx.x;
  for (int i = 0; i < 32; ++i) sW[t + i * 256] = W[t + i * 256];
  const int r0 = blockIdx.x * 16;
  for (int i = 0; i < 8; ++i) {
    int idx = t + i * 256;
    int r = idx >> 7, k = idx & 127;
    int gr = r0 + r;
    sX[idx] = (gr < N) ? x[gr * 128 + k] : 0.f;
  }
  __syncthreads();
  const int col = t & 63;
  const int rg = t >> 6;
  float a0 = 0.f, a1 = 0.f, a2 = 0.f, a3 = 0.f;
#pragma unroll 4
  for (int k = 0; k < 128; ++k) {
    float w = sW[k * 64 + col];
    a0 += sX[(rg + 0) * 128 + k] * w;
    a1 += sX[(rg + 4) * 128 + k] * w;
    a2 += sX[(rg + 8) * 128 + k] * w;
    a3 += sX[(rg + 12) * 128 + k] * w;
  }
  if (r0 + rg + 0 < N) h1[(r0 + rg + 0) * 64 + col] = a0;
  if (r0 + rg + 4 < N) h1[(r0 + rg + 4) * 64 + col] = a1;
  if (r0 + rg + 8 < N) h1[(r0 + rg + 8) * 64 + col] = a2;
  if (r0 + rg + 12 < N) h1[(r0 + rg + 12) * 64 + col] = a3;
}

// ---------------- scores layer1: es[N,2], ed[N,2] ----------------
__global__ __launch_bounds__(256) void k_scores1(const float* __restrict__ h1,
                                                 const float* __restrict__ a_src,
                                                 const float* __restrict__ a_dst,
                                                 float* __restrict__ es,
                                                 float* __restrict__ ed, int N) {
  int n = blockIdx.x * blockDim.x + threadIdx.x;
  if (n >= N) return;
  const float4* hp = (const float4*)(h1 + n * 64);
  const float4* as = (const float4*)a_src;
  const float4* ad = (const float4*)a_dst;
  float s[2] = {0.f, 0.f}, d[2] = {0.f, 0.f};
#pragma unroll
  for (int q = 0; q < 16; ++q) {
    float4 v = hp[q];
    float4 a = as[q];
    float4 b = ad[q];
    int hh = q >> 3;
    s[hh] += v.x * a.x + v.y * a.y + v.z * a.z + v.w * a.w;
    d[hh] += v.x * b.x + v.y * b.y + v.z * b.z + v.w * b.w;
  }
  es[n * 2 + 0] = s[0]; es[n * 2 + 1] = s[1];
  ed[n * 2 + 0] = d[0]; ed[n * 2 + 1] = d[1];
}

// -------- fused softmax+aggregate layer 1: one wave per dst node --------
__global__ __launch_bounds__(256) void k_agg1(const int* __restrict__ rowptr,
                                              const int* __restrict__ col,
                                              const float* __restrict__ h1,
                                              const float* __restrict__ es,
                                              const float* __restrict__ ed,
                                              const float* __restrict__ bias,
                                              float* __restrict__ out1, int N) {
  int d = (blockIdx.x * blockDim.x + threadIdx.x) >> 6;
  int lane = threadIdx.x & 63;
  if (d >= N) return;
  int g = lane >> 4;        // edge group 0..3
  int q = lane & 15;        // channel quad 0..15
  int ch = q * 4;
  int hh = ch >> 5;
  float edv = ed[d * 2 + hh];

  float4 acc = make_float4(0.f, 0.f, 0.f, 0.f);
  float wsum = 0.f;

  if (g == 0) {  // self-loop
    float v = es[d * 2 + hh] + edv;
    v = v > 0.f ? v : NEG_SLOPE * v;
    float w = __expf(v);
    float4 hv = *(const float4*)(h1 + (size_t)d * 64 + ch);
    acc.x = w * hv.x; acc.y = w * hv.y; acc.z = w * hv.z; acc.w = w * hv.w;
    wsum = w;
  }

  int beg = rowptr[d], end = rowptr[d + 1];
#pragma unroll 2
  for (int j = beg + g; j < end; j += 4) {
    int s = col[j];
    float vv = es[s * 2 + hh] + edv;
    vv = vv > 0.f ? vv : NEG_SLOPE * vv;
    float w = __expf(vv);
    float4 hv = *(const float4*)(h1 + (size_t)s * 64 + ch);
    acc.x += w * hv.x; acc.y += w * hv.y; acc.z += w * hv.z; acc.w += w * hv.w;
    wsum += w;
  }

#pragma unroll
  for (int off = 16; off <= 32; off <<= 1) {
    acc.x += __shfl_xor(acc.x, off);
    acc.y += __shfl_xor(acc.y, off);
    acc.z += __shfl_xor(acc.z, off);
    acc.w += __shfl_xor(acc.w, off);
    wsum  += __shfl_xor(wsum, off);
  }

  if (g == 0) {
    float inv = 1.f / (wsum + 1e-16f);
    const float4 bv = *(const float4*)(bias + ch);
    float4 o;
    o.x = acc.x * inv + bv.x;
    o.y = acc.y * inv + bv.y;
    o.z = acc.z * inv + bv.z;
    o.w = acc.w * inv + bv.w;
    *(float4*)(out1 + (size_t)d * 64 + ch) = o;
  }
}

// ---------------- GEMM2: hL2[N,32] = relu(out1)[N,64] @ W2[64,32] ----------------
__global__ __launch_bounds__(256) void k_gemm2(const float* __restrict__ out1,
                                               const float* __restrict__ W,
                                               float* __restrict__ hL2, int N) {
  __shared__ float sW[64 * 32];
  __shared__ float sX[32 * 64];
  const int t = threadIdx.x;
  for (int i = 0; i < 8; ++i) sW[t + i * 256] = W[t + i * 256];
  const int r0 = blockIdx.x * 32;
  for (int i = 0; i < 8; ++i) {
    int idx = t + i * 256;
    int r = idx >> 6, k = idx & 63;
    int gr = r0 + r;
    float v = (gr < N) ? out1[gr * 64 + k] : 0.f;
    sX[idx] = fmaxf(v, 0.f);  // fused ReLU
  }
  __syncthreads();
  const int col = t & 31;
  const int rg = t >> 5;
  float a0 = 0.f, a1 = 0.f, a2 = 0.f, a3 = 0.f;
#pragma unroll 4
  for (int k = 0; k < 64; ++k) {
    float w = sW[k * 32 + col];
    a0 += sX[(rg + 0) * 64 + k] * w;
    a1 += sX[(rg + 8) * 64 + k] * w;
    a2 += sX[(rg + 16) * 64 + k] * w;
    a3 += sX[(rg + 24) * 64 + k] * w;
  }
  if (r0 + rg + 0 < N) hL2[(r0 + rg + 0) * 32 + col] = a0;
  if (r0 + rg + 8 < N) hL2[(r0 + rg + 8) * 32 + col] = a1;
  if (r0 + rg + 16 < N) hL2[(r0 + rg + 16) * 32 + col] = a2;
  if (r0 + rg + 24 < N) hL2[(r0 + rg + 24) * 32 + col] = a3;
}

// ---------------- scores layer2 (1 head) ----------------
__global__ __launch_bounds__(256) void k_scores2(const float* __restrict__ hL2,
                                                 const float* __restrict__ a_src,
                                                 const float* __restrict__ a_dst,
                                                 float* __restrict__ es,
                                                 float* __restrict__ ed, int N) {
  int n = blockIdx.x * blockDim.x + threadIdx.x;
  if (n >= N) return;
  const float4* hp = (const float4*)(hL2 + n * 32);
  const float4* as = (const float4*)a_src;
  const float4* ad = (const float4*)a_dst;
  float s = 0.f, d = 0.f;
#pragma unroll
  for (int q = 0; q < 8; ++q) {
    float4 v = hp[q];
    float4 a = as[q];
    float4 b = ad[q];
    s += v.x * a.x + v.y * a.y + v.z * a.z + v.w * a.w;
    d += v.x * b.x + v.y * b.y + v.z * b.z + v.w * b.w;
  }
  es[n] = s;
  ed[n] = d;
}

// -------- fused softmax+aggregate layer 2: one wave per dst node --------
__global__ __launch_bounds__(256) void k_agg2(const int* __restrict__ rowptr,
                                              const int* __restrict__ col,
                                              const float* __restrict__ hL2,
                                              const float* __restrict__ es,
                                              const float* __restrict__ ed,
                                              const float* __restrict__ bias,
                                              float* __restrict__ out, int N) {
  int d = (blockIdx.x * blockDim.x + threadIdx.x) >> 6;
  int lane = threadIdx.x & 63;
  if (d >= N) return;
  int g = lane >> 3;       // edge group 0..7
  int q = lane & 7;        // channel quad 0..7
  int ch = q * 4;
  float edv = ed[d];

  float4 acc = make_float4(0.f, 0.f, 0.f, 0.f);
  float wsum = 0.f;

  if (g == 0) {
    float v = es[d] + edv;
    v = v > 0.f ? v : NEG_SLOPE * v;
    float w = __expf(v);
    float4 hv = *(const float4*)(hL2 + (size_t)d * 32 + ch);
    acc.x = w * hv.x; acc.y = w * hv.y; acc.z = w * hv.z; acc.w = w * hv.w;
    wsum = w;
  }

  int beg = rowptr[d], end = rowptr[d + 1];
#pragma unroll 2
  for (int j = beg + g; j < end; j += 8) {
    int s = col[j];
    float vv = es[s] + edv;
    vv = vv > 0.f ? vv : NEG_SLOPE * vv;
    float w = __expf(vv);
    float4 hv = *(const float4*)(hL2 + (size_t)s * 32 + ch);
    acc.x += w * hv.x; acc.y += w * hv.y; acc.z += w * hv.z; acc.w += w * hv.w;
    wsum += w;
  }

#pragma unroll
  for (int off = 8; off <= 32; off <<= 1) {
    acc.x += __shfl_xor(acc.x, off);
    acc.y += __shfl_xor(acc.y, off);
    acc.z += __shfl_xor(acc.z, off);
    acc.w += __shfl_xor(acc.w, off);
    wsum  += __shfl_xor(wsum, off);
  }

  if (g == 0) {
    float inv = 1.f / (wsum + 1e-16f);
    const float4 bv = *(const float4*)(bias + ch);
    float4 o;
    o.x = acc.x * inv + bv.x;
    o.y = acc.y * inv + bv.y;
    o.z = acc.z * inv + bv.z;
    o.w = acc.w * inv + bv.w;
    *(float4*)(out + (size_t)d * 32 + ch) = o;
  }
}

extern "C" void kernel_launch(void* const* d_in, const int* in_sizes, int n_in,
                              void* d_out, int out_size, void* d_ws, size_t ws_size,
                              hipStream_t stream) {
  const float* x      = (const float*)d_in[0];
  const int*   ei     = (const int*)d_in[1];
  const float* W1     = (const float*)d_in[2];
  const float* a_src1 = (const float*)d_in[3];
  const float* a_dst1 = (const float*)d_in[4];
  const float* b1     = (const float*)d_in[5];
  const float* W2     = (const float*)d_in[6];
  const float* a_src2 = (const float*)d_in[7];
  const float* a_dst2 = (const float*)d_in[8];
  const float* b2     = (const float*)d_in[9];
  float* out = (float*)d_out;

  const int N = in_sizes[0] / 128;
  const int E = in_sizes[1] / 2;
  const int NB = (N + DB - 1) / DB;
  const int* srcv = ei;
  const int* dstv = ei + E;

  // workspace carve (16B aligned chunks)
  char* base = (char*)d_ws;
  size_t off = 0;
  auto carve = [&](size_t bytes) {
    void* p = base + off;
    off += (bytes + 15) & ~(size_t)15;
    return p;
  };
  float* h1     = (float*)carve((size_t)N * 64 * 4);
  float* es1    = (float*)carve((size_t)N * 2 * 4);
  float* ed1    = (float*)carve((size_t)N * 2 * 4);
  float* out1   = (float*)carve((size_t)N * 64 * 4);
  float* hL2    = (float*)carve((size_t)N * 32 * 4);
  float* es2    = (float*)carve((size_t)N * 4);
  float* ed2    = (float*)carve((size_t)N * 4);
  int*   bcnt   = (int*)carve((size_t)NB_MAX * 4);
  int*   gbase  = (int*)carve((size_t)(NB_MAX + 1) * 4);
  int*   gcur   = (int*)carve((size_t)NB_MAX * 4);
  int*   rowptr = (int*)carve((size_t)(N + 1) * 4);
  int*   col    = (int*)carve((size_t)E * 4);
  int*   ebuf   = (int*)carve((size_t)E * 4);

  const int pblocks = (E + EPB - 1) / EPB;

  // ---- CSR build ----
  hipMemsetAsync(bcnt, 0, (size_t)NB_MAX * sizeof(int), stream);
  k_bhist<<<pblocks, 256, 0, stream>>>(dstv, bcnt, E);
  k_bscan<<<1, NB_MAX, 0, stream>>>(bcnt, gbase, gcur, rowptr, NB, N);
  k_part<<<pblocks, 256, 0, stream>>>(srcv, dstv, gcur, ebuf, E);
  k_csr<<<NB, 256, 0, stream>>>(gbase, ebuf, rowptr, col, N);

  // ---- layer 1 ----
  k_gemm1<<<(N + 15) / 16, 256, 0, stream>>>(x, W1, h1, N);
  k_scores1<<<(N + 255) / 256, 256, 0, stream>>>(h1, a_src1, a_dst1, es1, ed1, N);
  k_agg1<<<((size_t)N * 64 + 255) / 256, 256, 0, stream>>>(rowptr, col, h1, es1, ed1, b1, out1, N);

  // ---- layer 2 ----
  k_gemm2<<<(N + 31) / 32, 256, 0, stream>>>(out1, W2, hL2, N);
  k_scores2<<<(N + 255) / 256, 256, 0, stream>>>(hL2, a_src2, a_dst2, es2, ed2, N);
  k_agg2<<<((size_t)N * 64 + 255) / 256, 256, 0, stream>>>(rowptr, col, hL2, es2, ed2, b2, out, N);
}

// Round 5
// 253.898 us; speedup vs baseline: 3.7205x; 1.0789x over previous
//
#include <hip/hip_runtime.h>

#define NEG_SLOPE 0.2f
#define DB 128      // dst nodes per bucket
#define NB_MAX 512  // max buckets (N <= 65536)
#define EPB 4096    // edges per block in partition kernels

// ============ CSR build: two-phase LDS-binned counting sort ============

__global__ __launch_bounds__(256) void k_bhist(const int* __restrict__ dstv,
                                               int* __restrict__ bcnt, int E) {
  __shared__ int sh[NB_MAX];
  int t = threadIdx.x;
  sh[t] = 0; sh[t + 256] = 0;
  __syncthreads();
  int base = blockIdx.x * EPB;
#pragma unroll
  for (int i = 0; i < 16; ++i) {
    int e = base + i * 256 + t;
    if (e < E) atomicAdd(&sh[dstv[e] >> 7], 1);
  }
  __syncthreads();
#pragma unroll
  for (int i = 0; i < 2; ++i) {
    int b = t + 256 * i;
    int c = sh[b];
    if (c) atomicAdd(&bcnt[b], c);
  }
}

__global__ __launch_bounds__(NB_MAX) void k_bscan(const int* __restrict__ bcnt,
                                                  int* __restrict__ gbase,
                                                  int* __restrict__ gcur,
                                                  int* __restrict__ rowptr,
                                                  int NB, int N) {
  __shared__ int s[NB_MAX];
  int t = threadIdx.x;
  int v = (t < NB) ? bcnt[t] : 0;
  s[t] = v;
  __syncthreads();
  for (int off = 1; off < NB_MAX; off <<= 1) {
    int u = (t >= off) ? s[t - off] : 0;
    __syncthreads();
    s[t] += u;
    __syncthreads();
  }
  int excl = s[t] - v;
  if (t < NB) { gbase[t] = excl; gcur[t] = excl; }
  if (t == NB - 1) { gbase[NB] = s[t]; rowptr[N] = s[t]; }
}

__global__ __launch_bounds__(256) void k_part(const int* __restrict__ srcv,
                                              const int* __restrict__ dstv,
                                              int* __restrict__ gcur,
                                              int* __restrict__ ebuf, int E) {
  __shared__ int sh[NB_MAX];
  __shared__ int lbase[NB_MAX];
  int t = threadIdx.x;
  sh[t] = 0; sh[t + 256] = 0;
  __syncthreads();
  int base = blockIdx.x * EPB;
  int dd[16];
#pragma unroll
  for (int i = 0; i < 16; ++i) {
    int e = base + i * 256 + t;
    dd[i] = (e < E) ? dstv[e] : -1;
    if (dd[i] >= 0) atomicAdd(&sh[dd[i] >> 7], 1);
  }
  __syncthreads();
#pragma unroll
  for (int i = 0; i < 2; ++i) {
    int b = t + 256 * i;
    int c = sh[b];
    lbase[b] = c ? atomicAdd(&gcur[b], c) : 0;
    sh[b] = 0;  // becomes local cursor
  }
  __syncthreads();
#pragma unroll
  for (int i = 0; i < 16; ++i) {
    if (dd[i] >= 0) {
      int e = base + i * 256 + t;
      int b = dd[i] >> 7;
      int r = atomicAdd(&sh[b], 1);
      ebuf[lbase[b] + r] = srcv[e] | ((dd[i] & 127) << 16);
    }
  }
}

__global__ __launch_bounds__(256) void k_csr(const int* __restrict__ gbase,
                                             const int* __restrict__ ebuf,
                                             int* __restrict__ rowptr,
                                             int* __restrict__ col, int N) {
  int b = blockIdx.x;
  int base = gbase[b];
  int cnt = gbase[b + 1] - base;
  int dbase = b * DB;
  __shared__ int dh[DB];
  __shared__ int sc[DB];
  int t = threadIdx.x;
  if (t < DB) dh[t] = 0;
  __syncthreads();
  for (int j = t; j < cnt; j += 256) {
    int p = ebuf[base + j];
    atomicAdd(&dh[p >> 16], 1);
  }
  __syncthreads();
  int v = 0;
  if (t < DB) { v = dh[t]; sc[t] = v; }
  __syncthreads();
  for (int off = 1; off < DB; off <<= 1) {
    int u = 0;
    if (t < DB && t >= off) u = sc[t - off];
    __syncthreads();
    if (t < DB) sc[t] += u;
    __syncthreads();
  }
  if (t < DB) {
    int excl = sc[t] - v;
    int d = dbase + t;
    if (d < N) rowptr[d] = base + excl;
    dh[t] = base + excl;
  }
  __syncthreads();
  for (int j = t; j < cnt; j += 256) {
    int p = ebuf[base + j];
    int r = atomicAdd(&dh[p >> 16], 1);
    col[r] = p & 0xFFFF;
  }
}

// ======== GEMM1 + fused scores1: h1 = x@W1 ; es1/ed1 = h1 . a_{src,dst}1 ========
// M=64 tile, N=64, K=128. 256 thr: tx=t&15 (4 cols), ty=t>>4 (4 rows). 16 acc.
__global__ __launch_bounds__(256) void k_gemm1(const float* __restrict__ x,
                                               const float* __restrict__ W,
                                               const float* __restrict__ a_src,
                                               const float* __restrict__ a_dst,
                                               float* __restrict__ h1,
                                               float* __restrict__ es,
                                               float* __restrict__ ed, int N) {
  __shared__ float sXT[128 * 64];  // [k][row], 32 KB
  __shared__ float sW[128 * 64];   // [k][col], 32 KB (W1 is k-major already)
  const int t = threadIdx.x;
  const int r0 = blockIdx.x * 64;

  // stage W: direct copy, coalesced float4
  {
    const float4* Wp = (const float4*)W;
    float4* sWp = (float4*)sW;
#pragma unroll
    for (int i = 0; i < 8; ++i) sWp[t + i * 256] = Wp[t + i * 256];
  }
  // stage x transposed: thread loads x[r0 + (t&63)][k..k+3] for 8 k-quads
  {
    int r = t & 63;
    int kq = t >> 6;  // 0..3
    int gr = r0 + r;
    bool ok = gr < N;
    const float* xr = x + (size_t)gr * 128;
#pragma unroll
    for (int p = 0; p < 8; ++p) {
      int k = (kq + p * 4) * 4;  // kq*4 + p*16
      float4 v = ok ? *(const float4*)(xr + k) : make_float4(0.f, 0.f, 0.f, 0.f);
      sXT[(k + 0) * 64 + r] = v.x;
      sXT[(k + 1) * 64 + r] = v.y;
      sXT[(k + 2) * 64 + r] = v.z;
      sXT[(k + 3) * 64 + r] = v.w;
    }
  }
  __syncthreads();

  const int tx = t & 15, ty = t >> 4;
  float4 acc0 = make_float4(0.f, 0.f, 0.f, 0.f);
  float4 acc1 = acc0, acc2 = acc0, acc3 = acc0;
#pragma unroll 8
  for (int k = 0; k < 128; ++k) {
    float4 av = *(const float4*)(sXT + k * 64 + ty * 4);
    float4 bv = *(const float4*)(sW + k * 64 + tx * 4);
    acc0.x += av.x * bv.x; acc0.y += av.x * bv.y; acc0.z += av.x * bv.z; acc0.w += av.x * bv.w;
    acc1.x += av.y * bv.x; acc1.y += av.y * bv.y; acc1.z += av.y * bv.z; acc1.w += av.y * bv.w;
    acc2.x += av.z * bv.x; acc2.y += av.z * bv.y; acc2.z += av.z * bv.z; acc2.w += av.z * bv.w;
    acc3.x += av.w * bv.x; acc3.y += av.w * bv.y; acc3.z += av.w * bv.z; acc3.w += av.w * bv.w;
  }

  // write h1 tile
  float4 accs[4] = {acc0, acc1, acc2, acc3};
#pragma unroll
  for (int i = 0; i < 4; ++i) {
    int gr = r0 + ty * 4 + i;
    if (gr < N) *(float4*)(h1 + (size_t)gr * 64 + tx * 4) = accs[i];
  }

  // fused scores: per row dot with a_src/a_dst (64 floats each, col-aligned)
  float4 asv = *(const float4*)(a_src + tx * 4);
  float4 adv = *(const float4*)(a_dst + tx * 4);
  float esp[4], edp[4];
#pragma unroll
  for (int i = 0; i < 4; ++i) {
    esp[i] = accs[i].x * asv.x + accs[i].y * asv.y + accs[i].z * asv.z + accs[i].w * asv.w;
    edp[i] = accs[i].x * adv.x + accs[i].y * adv.y + accs[i].z * adv.z + accs[i].w * adv.w;
  }
#pragma unroll
  for (int off = 1; off <= 4; off <<= 1) {
#pragma unroll
    for (int i = 0; i < 4; ++i) {
      esp[i] += __shfl_xor(esp[i], off);
      edp[i] += __shfl_xor(edp[i], off);
    }
  }
  if ((tx & 7) == 0) {
    int hh = tx >> 3;
#pragma unroll
    for (int i = 0; i < 4; ++i) {
      int gr = r0 + ty * 4 + i;
      if (gr < N) {
        es[gr * 2 + hh] = esp[i];
        ed[gr * 2 + hh] = edp[i];
      }
    }
  }
}

// -------- fused softmax+aggregate layer 1: one wave per dst node --------
__global__ __launch_bounds__(256) void k_agg1(const int* __restrict__ rowptr,
                                              const int* __restrict__ col,
                                              const float* __restrict__ h1,
                                              const float* __restrict__ es,
                                              const float* __restrict__ ed,
                                              const float* __restrict__ bias,
                                              float* __restrict__ out1, int N) {
  int d = (blockIdx.x * blockDim.x + threadIdx.x) >> 6;
  int lane = threadIdx.x & 63;
  if (d >= N) return;
  int g = lane >> 4;
  int q = lane & 15;
  int ch = q * 4;
  int hh = ch >> 5;
  float edv = ed[d * 2 + hh];

  float4 acc = make_float4(0.f, 0.f, 0.f, 0.f);
  float wsum = 0.f;

  if (g == 0) {  // self-loop
    float v = es[d * 2 + hh] + edv;
    v = v > 0.f ? v : NEG_SLOPE * v;
    float w = __expf(v);
    float4 hv = *(const float4*)(h1 + (size_t)d * 64 + ch);
    acc.x = w * hv.x; acc.y = w * hv.y; acc.z = w * hv.z; acc.w = w * hv.w;
    wsum = w;
  }

  int beg = rowptr[d], end = rowptr[d + 1];
#pragma unroll 2
  for (int j = beg + g; j < end; j += 4) {
    int s = col[j];
    float vv = es[s * 2 + hh] + edv;
    vv = vv > 0.f ? vv : NEG_SLOPE * vv;
    float w = __expf(vv);
    float4 hv = *(const float4*)(h1 + (size_t)s * 64 + ch);
    acc.x += w * hv.x; acc.y += w * hv.y; acc.z += w * hv.z; acc.w += w * hv.w;
    wsum += w;
  }

#pragma unroll
  for (int off = 16; off <= 32; off <<= 1) {
    acc.x += __shfl_xor(acc.x, off);
    acc.y += __shfl_xor(acc.y, off);
    acc.z += __shfl_xor(acc.z, off);
    acc.w += __shfl_xor(acc.w, off);
    wsum  += __shfl_xor(wsum, off);
  }

  if (g == 0) {
    float inv = 1.f / (wsum + 1e-16f);
    const float4 bv = *(const float4*)(bias + ch);
    float4 o;
    o.x = acc.x * inv + bv.x;
    o.y = acc.y * inv + bv.y;
    o.z = acc.z * inv + bv.z;
    o.w = acc.w * inv + bv.w;
    *(float4*)(out1 + (size_t)d * 64 + ch) = o;
  }
}

// ======== GEMM2 + fused scores2: hL2 = relu(out1)@W2 ; es2/ed2 ========
// M=128 tile, N=32, K=64. 256 thr: tx=t&7 (4 cols), ty=t>>3 (4 rows).
__global__ __launch_bounds__(256) void k_gemm2(const float* __restrict__ out1,
                                               const float* __restrict__ W,
                                               const float* __restrict__ a_src,
                                               const float* __restrict__ a_dst,
                                               float* __restrict__ hL2,
                                               float* __restrict__ es,
                                               float* __restrict__ ed, int N) {
  __shared__ float sXT[64 * 128];  // [k][row], 32 KB
  __shared__ float sW[64 * 32];    // [k][col], 8 KB (W2 is k-major already)
  const int t = threadIdx.x;
  const int r0 = blockIdx.x * 128;

  {
    const float4* Wp = (const float4*)W;
    float4* sWp = (float4*)sW;
#pragma unroll
    for (int i = 0; i < 2; ++i) sWp[t + i * 256] = Wp[t + i * 256];
  }
  {
    int r = t & 127;
    int kq = t >> 7;  // 0..1
    int gr = r0 + r;
    bool ok = gr < N;
    const float* xr = out1 + (size_t)gr * 64;
#pragma unroll
    for (int p = 0; p < 8; ++p) {
      int k = (kq + p * 2) * 4;  // kq*4 + p*8
      float4 v = ok ? *(const float4*)(xr + k) : make_float4(0.f, 0.f, 0.f, 0.f);
      sXT[(k + 0) * 128 + r] = fmaxf(v.x, 0.f);
      sXT[(k + 1) * 128 + r] = fmaxf(v.y, 0.f);
      sXT[(k + 2) * 128 + r] = fmaxf(v.z, 0.f);
      sXT[(k + 3) * 128 + r] = fmaxf(v.w, 0.f);
    }
  }
  __syncthreads();

  const int tx = t & 7, ty = t >> 3;
  float4 acc0 = make_float4(0.f, 0.f, 0.f, 0.f);
  float4 acc1 = acc0, acc2 = acc0, acc3 = acc0;
#pragma unroll 8
  for (int k = 0; k < 64; ++k) {
    float4 av = *(const float4*)(sXT + k * 128 + ty * 4);
    float4 bv = *(const float4*)(sW + k * 32 + tx * 4);
    acc0.x += av.x * bv.x; acc0.y += av.x * bv.y; acc0.z += av.x * bv.z; acc0.w += av.x * bv.w;
    acc1.x += av.y * bv.x; acc1.y += av.y * bv.y; acc1.z += av.y * bv.z; acc1.w += av.y * bv.w;
    acc2.x += av.z * bv.x; acc2.y += av.z * bv.y; acc2.z += av.z * bv.z; acc2.w += av.z * bv.w;
    acc3.x += av.w * bv.x; acc3.y += av.w * bv.y; acc3.z += av.w * bv.z; acc3.w += av.w * bv.w;
  }

  float4 accs[4] = {acc0, acc1, acc2, acc3};
#pragma unroll
  for (int i = 0; i < 4; ++i) {
    int gr = r0 + ty * 4 + i;
    if (gr < N) *(float4*)(hL2 + (size_t)gr * 32 + tx * 4) = accs[i];
  }

  float4 asv = *(const float4*)(a_src + tx * 4);
  float4 adv = *(const float4*)(a_dst + tx * 4);
  float esp[4], edp[4];
#pragma unroll
  for (int i = 0; i < 4; ++i) {
    esp[i] = accs[i].x * asv.x + accs[i].y * asv.y + accs[i].z * asv.z + accs[i].w * asv.w;
    edp[i] = accs[i].x * adv.x + accs[i].y * adv.y + accs[i].z * adv.z + accs[i].w * adv.w;
  }
#pragma unroll
  for (int off = 1; off <= 4; off <<= 1) {
#pragma unroll
    for (int i = 0; i < 4; ++i) {
      esp[i] += __shfl_xor(esp[i], off);
      edp[i] += __shfl_xor(edp[i], off);
    }
  }
  if (tx == 0) {
#pragma unroll
    for (int i = 0; i < 4; ++i) {
      int gr = r0 + ty * 4 + i;
      if (gr < N) {
        es[gr] = esp[i];
        ed[gr] = edp[i];
      }
    }
  }
}

// -------- fused softmax+aggregate layer 2: one wave per dst node --------
__global__ __launch_bounds__(256) void k_agg2(const int* __restrict__ rowptr,
                                              const int* __restrict__ col,
                                              const float* __restrict__ hL2,
                                              const float* __restrict__ es,
                                              const float* __restrict__ ed,
                                              const float* __restrict__ bias,
                                              float* __restrict__ out, int N) {
  int d = (blockIdx.x * blockDim.x + threadIdx.x) >> 6;
  int lane = threadIdx.x & 63;
  if (d >= N) return;
  int g = lane >> 3;
  int q = lane & 7;
  int ch = q * 4;
  float edv = ed[d];

  float4 acc = make_float4(0.f, 0.f, 0.f, 0.f);
  float wsum = 0.f;

  if (g == 0) {
    float v = es[d] + edv;
    v = v > 0.f ? v : NEG_SLOPE * v;
    float w = __expf(v);
    float4 hv = *(const float4*)(hL2 + (size_t)d * 32 + ch);
    acc.x = w * hv.x; acc.y = w * hv.y; acc.z = w * hv.z; acc.w = w * hv.w;
    wsum = w;
  }

  int beg = rowptr[d], end = rowptr[d + 1];
#pragma unroll 2
  for (int j = beg + g; j < end; j += 8) {
    int s = col[j];
    float vv = es[s] + edv;
    vv = vv > 0.f ? vv : NEG_SLOPE * vv;
    float w = __expf(vv);
    float4 hv = *(const float4*)(hL2 + (size_t)s * 32 + ch);
    acc.x += w * hv.x; acc.y += w * hv.y; acc.z += w * hv.z; acc.w += w * hv.w;
    wsum += w;
  }

#pragma unroll
  for (int off = 8; off <= 32; off <<= 1) {
    acc.x += __shfl_xor(acc.x, off);
    acc.y += __shfl_xor(acc.y, off);
    acc.z += __shfl_xor(acc.z, off);
    acc.w += __shfl_xor(acc.w, off);
    wsum  += __shfl_xor(wsum, off);
  }

  if (g == 0) {
    float inv = 1.f / (wsum + 1e-16f);
    const float4 bv = *(const float4*)(bias + ch);
    float4 o;
    o.x = acc.x * inv + bv.x;
    o.y = acc.y * inv + bv.y;
    o.z = acc.z * inv + bv.z;
    o.w = acc.w * inv + bv.w;
    *(float4*)(out + (size_t)d * 32 + ch) = o;
  }
}

extern "C" void kernel_launch(void* const* d_in, const int* in_sizes, int n_in,
                              void* d_out, int out_size, void* d_ws, size_t ws_size,
                              hipStream_t stream) {
  const float* x      = (const float*)d_in[0];
  const int*   ei     = (const int*)d_in[1];
  const float* W1     = (const float*)d_in[2];
  const float* a_src1 = (const float*)d_in[3];
  const float* a_dst1 = (const float*)d_in[4];
  const float* b1     = (const float*)d_in[5];
  const float* W2     = (const float*)d_in[6];
  const float* a_src2 = (const float*)d_in[7];
  const float* a_dst2 = (const float*)d_in[8];
  const float* b2     = (const float*)d_in[9];
  float* out = (float*)d_out;

  const int N = in_sizes[0] / 128;
  const int E = in_sizes[1] / 2;
  const int NB = (N + DB - 1) / DB;
  const int* srcv = ei;
  const int* dstv = ei + E;

  char* base = (char*)d_ws;
  size_t off = 0;
  auto carve = [&](size_t bytes) {
    void* p = base + off;
    off += (bytes + 15) & ~(size_t)15;
    return p;
  };
  float* h1     = (float*)carve((size_t)N * 64 * 4);
  float* es1    = (float*)carve((size_t)N * 2 * 4);
  float* ed1    = (float*)carve((size_t)N * 2 * 4);
  float* out1   = (float*)carve((size_t)N * 64 * 4);
  float* hL2    = (float*)carve((size_t)N * 32 * 4);
  float* es2    = (float*)carve((size_t)N * 4);
  float* ed2    = (float*)carve((size_t)N * 4);
  int*   bcnt   = (int*)carve((size_t)NB_MAX * 4);
  int*   gbase  = (int*)carve((size_t)(NB_MAX + 1) * 4);
  int*   gcur   = (int*)carve((size_t)NB_MAX * 4);
  int*   rowptr = (int*)carve((size_t)(N + 1) * 4);
  int*   col    = (int*)carve((size_t)E * 4);
  int*   ebuf   = (int*)carve((size_t)E * 4);

  const int pblocks = (E + EPB - 1) / EPB;

  // ---- CSR build ----
  hipMemsetAsync(bcnt, 0, (size_t)NB_MAX * sizeof(int), stream);
  k_bhist<<<pblocks, 256, 0, stream>>>(dstv, bcnt, E);
  k_bscan<<<1, NB_MAX, 0, stream>>>(bcnt, gbase, gcur, rowptr, NB, N);
  k_part<<<pblocks, 256, 0, stream>>>(srcv, dstv, gcur, ebuf, E);
  k_csr<<<NB, 256, 0, stream>>>(gbase, ebuf, rowptr, col, N);

  // ---- layer 1 ----
  k_gemm1<<<(N + 63) / 64, 256, 0, stream>>>(x, W1, a_src1, a_dst1, h1, es1, ed1, N);
  k_agg1<<<((size_t)N * 64 + 255) / 256, 256, 0, stream>>>(rowptr, col, h1, es1, ed1, b1, out1, N);

  // ---- layer 2 ----
  k_gemm2<<<(N + 127) / 128, 256, 0, stream>>>(out1, W2, a_src2, a_dst2, hL2, es2, ed2, N);
  k_agg2<<<((size_t)N * 64 + 255) / 256, 256, 0, stream>>>(rowptr, col, hL2, es2, ed2, b2, out, N);
}

// Round 6
// 222.406 us; speedup vs baseline: 4.2473x; 1.1416x over previous
//
#include <hip/hip_runtime.h>
#include <hip/hip_fp16.h>

#define NEG_SLOPE 0.2f
#define DB 128       // dst nodes per bucket
#define NB_MAX 512   // max buckets (N <= 65536)
#define EPB 4096     // edges per block in partition kernel
#define CAP 8192     // fixed capacity per bucket segment (mean load 4092)

// ============ CSR build: fixed-capacity bucket partition + local sort ============

// Phase 1: partition edges into fixed-cap bucket segments, packed (dlow<<16)|src
__global__ __launch_bounds__(256) void k_part(const int* __restrict__ srcv,
                                              const int* __restrict__ dstv,
                                              int* __restrict__ gcur,
                                              int* __restrict__ ebuf, int E) {
  __shared__ int sh[NB_MAX];
  __shared__ int lbase[NB_MAX];
  int t = threadIdx.x;
  sh[t] = 0; sh[t + 256] = 0;
  __syncthreads();
  int base = blockIdx.x * EPB;
  int dd[16];
#pragma unroll
  for (int i = 0; i < 16; ++i) {
    int e = base + i * 256 + t;
    dd[i] = (e < E) ? dstv[e] : -1;
    if (dd[i] >= 0) atomicAdd(&sh[dd[i] >> 7], 1);
  }
  __syncthreads();
#pragma unroll
  for (int i = 0; i < 2; ++i) {
    int b = t + 256 * i;
    int c = sh[b];
    lbase[b] = c ? (b * CAP + atomicAdd(&gcur[b], c)) : 0;
    sh[b] = 0;  // becomes local cursor
  }
  __syncthreads();
#pragma unroll
  for (int i = 0; i < 16; ++i) {
    if (dd[i] >= 0) {
      int e = base + i * 256 + t;
      int b = dd[i] >> 7;
      int r = atomicAdd(&sh[b], 1);
      ebuf[lbase[b] + r] = srcv[e] | ((dd[i] & 127) << 16);
    }
  }
}

// Phase 2: per-bucket local counting sort -> rowbeg/rowend + col (bucket-segmented)
__global__ __launch_bounds__(256) void k_csr(const int* __restrict__ gcur,
                                             const int* __restrict__ ebuf,
                                             int* __restrict__ rowbeg,
                                             int* __restrict__ rowend,
                                             int* __restrict__ col, int N) {
  int b = blockIdx.x;
  int cnt = gcur[b];
  int base = b * CAP;
  int dbase = b * DB;
  __shared__ int dh[DB];
  __shared__ int sc[DB];
  int t = threadIdx.x;
  if (t < DB) dh[t] = 0;
  __syncthreads();
  for (int j = t; j < cnt; j += 256) {
    int p = ebuf[base + j];
    atomicAdd(&dh[p >> 16], 1);
  }
  __syncthreads();
  int v = 0;
  if (t < DB) { v = dh[t]; sc[t] = v; }
  __syncthreads();
  for (int off = 1; off < DB; off <<= 1) {
    int u = 0;
    if (t < DB && t >= off) u = sc[t - off];
    __syncthreads();
    if (t < DB) sc[t] += u;
    __syncthreads();
  }
  if (t < DB) {
    int excl = sc[t] - v;
    int d = dbase + t;
    if (d < N) {
      rowbeg[d] = base + excl;
      rowend[d] = base + excl + v;
    }
    dh[t] = base + excl;
  }
  __syncthreads();
  for (int j = t; j < cnt; j += 256) {
    int p = ebuf[base + j];
    int r = atomicAdd(&dh[p >> 16], 1);
    col[r] = p & 0xFFFF;
  }
}

// ======== GEMM1 + fused scores1: h1(fp16) = x@W1 ; es1/ed1 = h1 . a ========
__global__ __launch_bounds__(256) void k_gemm1(const float* __restrict__ x,
                                               const float* __restrict__ W,
                                               const float* __restrict__ a_src,
                                               const float* __restrict__ a_dst,
                                               __half* __restrict__ h1,
                                               float* __restrict__ es,
                                               float* __restrict__ ed, int N) {
  __shared__ float sXT[128 * 64];
  __shared__ float sW[128 * 64];
  const int t = threadIdx.x;
  const int r0 = blockIdx.x * 64;

  {
    const float4* Wp = (const float4*)W;
    float4* sWp = (float4*)sW;
#pragma unroll
    for (int i = 0; i < 8; ++i) sWp[t + i * 256] = Wp[t + i * 256];
  }
  {
    int r = t & 63;
    int kq = t >> 6;
    int gr = r0 + r;
    bool ok = gr < N;
    const float* xr = x + (size_t)gr * 128;
#pragma unroll
    for (int p = 0; p < 8; ++p) {
      int k = (kq + p * 4) * 4;
      float4 v = ok ? *(const float4*)(xr + k) : make_float4(0.f, 0.f, 0.f, 0.f);
      sXT[(k + 0) * 64 + r] = v.x;
      sXT[(k + 1) * 64 + r] = v.y;
      sXT[(k + 2) * 64 + r] = v.z;
      sXT[(k + 3) * 64 + r] = v.w;
    }
  }
  __syncthreads();

  const int tx = t & 15, ty = t >> 4;
  float4 acc0 = make_float4(0.f, 0.f, 0.f, 0.f);
  float4 acc1 = acc0, acc2 = acc0, acc3 = acc0;
#pragma unroll 8
  for (int k = 0; k < 128; ++k) {
    float4 av = *(const float4*)(sXT + k * 64 + ty * 4);
    float4 bv = *(const float4*)(sW + k * 64 + tx * 4);
    acc0.x += av.x * bv.x; acc0.y += av.x * bv.y; acc0.z += av.x * bv.z; acc0.w += av.x * bv.w;
    acc1.x += av.y * bv.x; acc1.y += av.y * bv.y; acc1.z += av.y * bv.z; acc1.w += av.y * bv.w;
    acc2.x += av.z * bv.x; acc2.y += av.z * bv.y; acc2.z += av.z * bv.z; acc2.w += av.z * bv.w;
    acc3.x += av.w * bv.x; acc3.y += av.w * bv.y; acc3.z += av.w * bv.z; acc3.w += av.w * bv.w;
  }

  float4 accs[4] = {acc0, acc1, acc2, acc3};
#pragma unroll
  for (int i = 0; i < 4; ++i) {
    int gr = r0 + ty * 4 + i;
    if (gr < N) {
      union { __half2 h[2]; float2 f; } u;
      u.h[0] = __float22half2_rn(make_float2(accs[i].x, accs[i].y));
      u.h[1] = __float22half2_rn(make_float2(accs[i].z, accs[i].w));
      *(float2*)(h1 + (size_t)gr * 64 + tx * 4) = u.f;
    }
  }

  float4 asv = *(const float4*)(a_src + tx * 4);
  float4 adv = *(const float4*)(a_dst + tx * 4);
  float esp[4], edp[4];
#pragma unroll
  for (int i = 0; i < 4; ++i) {
    esp[i] = accs[i].x * asv.x + accs[i].y * asv.y + accs[i].z * asv.z + accs[i].w * asv.w;
    edp[i] = accs[i].x * adv.x + accs[i].y * adv.y + accs[i].z * adv.z + accs[i].w * adv.w;
  }
#pragma unroll
  for (int off = 1; off <= 4; off <<= 1) {
#pragma unroll
    for (int i = 0; i < 4; ++i) {
      esp[i] += __shfl_xor(esp[i], off);
      edp[i] += __shfl_xor(edp[i], off);
    }
  }
  if ((tx & 7) == 0) {
    int hh = tx >> 3;
#pragma unroll
    for (int i = 0; i < 4; ++i) {
      int gr = r0 + ty * 4 + i;
      if (gr < N) {
        es[gr * 2 + hh] = esp[i];
        ed[gr * 2 + hh] = edp[i];
      }
    }
  }
}

// -------- fused softmax+aggregate layer 1: one wave per dst node (fp16 gather) --------
__global__ __launch_bounds__(256) void k_agg1(const int* __restrict__ rowbeg,
                                              const int* __restrict__ rowend,
                                              const int* __restrict__ col,
                                              const __half* __restrict__ h1,
                                              const float* __restrict__ es,
                                              const float* __restrict__ ed,
                                              const float* __restrict__ bias,
                                              float* __restrict__ out1, int N) {
  int d = (blockIdx.x * blockDim.x + threadIdx.x) >> 6;
  int lane = threadIdx.x & 63;
  if (d >= N) return;
  int g = lane >> 4;
  int q = lane & 15;
  int ch = q * 4;
  int hh = ch >> 5;
  float edv = ed[d * 2 + hh];

  float4 acc = make_float4(0.f, 0.f, 0.f, 0.f);
  float wsum = 0.f;

  if (g == 0) {  // self-loop
    float v = es[d * 2 + hh] + edv;
    v = v > 0.f ? v : NEG_SLOPE * v;
    float w = __expf(v);
    float2 raw = *(const float2*)(h1 + (size_t)d * 64 + ch);
    __half2* p2 = (__half2*)&raw;
    float2 lo = __half22float2(p2[0]);
    float2 hi = __half22float2(p2[1]);
    acc.x = w * lo.x; acc.y = w * lo.y; acc.z = w * hi.x; acc.w = w * hi.y;
    wsum = w;
  }

  int beg = rowbeg[d], end = rowend[d];
#pragma unroll 2
  for (int j = beg + g; j < end; j += 4) {
    int s = col[j];
    float vv = es[s * 2 + hh] + edv;
    vv = vv > 0.f ? vv : NEG_SLOPE * vv;
    float w = __expf(vv);
    float2 raw = *(const float2*)(h1 + (size_t)s * 64 + ch);
    __half2* p2 = (__half2*)&raw;
    float2 lo = __half22float2(p2[0]);
    float2 hi = __half22float2(p2[1]);
    acc.x += w * lo.x; acc.y += w * lo.y; acc.z += w * hi.x; acc.w += w * hi.y;
    wsum += w;
  }

#pragma unroll
  for (int off = 16; off <= 32; off <<= 1) {
    acc.x += __shfl_xor(acc.x, off);
    acc.y += __shfl_xor(acc.y, off);
    acc.z += __shfl_xor(acc.z, off);
    acc.w += __shfl_xor(acc.w, off);
    wsum  += __shfl_xor(wsum, off);
  }

  if (g == 0) {
    float inv = 1.f / (wsum + 1e-16f);
    const float4 bv = *(const float4*)(bias + ch);
    float4 o;
    o.x = acc.x * inv + bv.x;
    o.y = acc.y * inv + bv.y;
    o.z = acc.z * inv + bv.z;
    o.w = acc.w * inv + bv.w;
    *(float4*)(out1 + (size_t)d * 64 + ch) = o;
  }
}

// ======== GEMM2 + fused scores2: hL2(fp16) = relu(out1)@W2 ; es2/ed2 ========
__global__ __launch_bounds__(256) void k_gemm2(const float* __restrict__ out1,
                                               const float* __restrict__ W,
                                               const float* __restrict__ a_src,
                                               const float* __restrict__ a_dst,
                                               __half* __restrict__ hL2,
                                               float* __restrict__ es,
                                               float* __restrict__ ed, int N) {
  __shared__ float sXT[64 * 128];
  __shared__ float sW[64 * 32];
  const int t = threadIdx.x;
  const int r0 = blockIdx.x * 128;

  {
    const float4* Wp = (const float4*)W;
    float4* sWp = (float4*)sW;
#pragma unroll
    for (int i = 0; i < 2; ++i) sWp[t + i * 256] = Wp[t + i * 256];
  }
  {
    int r = t & 127;
    int kq = t >> 7;
    int gr = r0 + r;
    bool ok = gr < N;
    const float* xr = out1 + (size_t)gr * 64;
#pragma unroll
    for (int p = 0; p < 8; ++p) {
      int k = (kq + p * 2) * 4;
      float4 v = ok ? *(const float4*)(xr + k) : make_float4(0.f, 0.f, 0.f, 0.f);
      sXT[(k + 0) * 128 + r] = fmaxf(v.x, 0.f);
      sXT[(k + 1) * 128 + r] = fmaxf(v.y, 0.f);
      sXT[(k + 2) * 128 + r] = fmaxf(v.z, 0.f);
      sXT[(k + 3) * 128 + r] = fmaxf(v.w, 0.f);
    }
  }
  __syncthreads();

  const int tx = t & 7, ty = t >> 3;
  float4 acc0 = make_float4(0.f, 0.f, 0.f, 0.f);
  float4 acc1 = acc0, acc2 = acc0, acc3 = acc0;
#pragma unroll 8
  for (int k = 0; k < 64; ++k) {
    float4 av = *(const float4*)(sXT + k * 128 + ty * 4);
    float4 bv = *(const float4*)(sW + k * 32 + tx * 4);
    acc0.x += av.x * bv.x; acc0.y += av.x * bv.y; acc0.z += av.x * bv.z; acc0.w += av.x * bv.w;
    acc1.x += av.y * bv.x; acc1.y += av.y * bv.y; acc1.z += av.y * bv.z; acc1.w += av.y * bv.w;
    acc2.x += av.z * bv.x; acc2.y += av.z * bv.y; acc2.z += av.z * bv.z; acc2.w += av.z * bv.w;
    acc3.x += av.w * bv.x; acc3.y += av.w * bv.y; acc3.z += av.w * bv.z; acc3.w += av.w * bv.w;
  }

  float4 accs[4] = {acc0, acc1, acc2, acc3};
#pragma unroll
  for (int i = 0; i < 4; ++i) {
    int gr = r0 + ty * 4 + i;
    if (gr < N) {
      union { __half2 h[2]; float2 f; } u;
      u.h[0] = __float22half2_rn(make_float2(accs[i].x, accs[i].y));
      u.h[1] = __float22half2_rn(make_float2(accs[i].z, accs[i].w));
      *(float2*)(hL2 + (size_t)gr * 32 + tx * 4) = u.f;
    }
  }

  float4 asv = *(const float4*)(a_src + tx * 4);
  float4 adv = *(const float4*)(a_dst + tx * 4);
  float esp[4], edp[4];
#pragma unroll
  for (int i = 0; i < 4; ++i) {
    esp[i] = accs[i].x * asv.x + accs[i].y * asv.y + accs[i].z * asv.z + accs[i].w * asv.w;
    edp[i] = accs[i].x * adv.x + accs[i].y * adv.y + accs[i].z * adv.z + accs[i].w * adv.w;
  }
#pragma unroll
  for (int off = 1; off <= 4; off <<= 1) {
#pragma unroll
    for (int i = 0; i < 4; ++i) {
      esp[i] += __shfl_xor(esp[i], off);
      edp[i] += __shfl_xor(edp[i], off);
    }
  }
  if (tx == 0) {
#pragma unroll
    for (int i = 0; i < 4; ++i) {
      int gr = r0 + ty * 4 + i;
      if (gr < N) {
        es[gr] = esp[i];
        ed[gr] = edp[i];
      }
    }
  }
}

// -------- fused softmax+aggregate layer 2: one wave per dst node (fp16 gather) --------
__global__ __launch_bounds__(256) void k_agg2(const int* __restrict__ rowbeg,
                                              const int* __restrict__ rowend,
                                              const int* __restrict__ col,
                                              const __half* __restrict__ hL2,
                                              const float* __restrict__ es,
                                              const float* __restrict__ ed,
                                              const float* __restrict__ bias,
                                              float* __restrict__ out, int N) {
  int d = (blockIdx.x * blockDim.x + threadIdx.x) >> 6;
  int lane = threadIdx.x & 63;
  if (d >= N) return;
  int g = lane >> 3;
  int q = lane & 7;
  int ch = q * 4;
  float edv = ed[d];

  float4 acc = make_float4(0.f, 0.f, 0.f, 0.f);
  float wsum = 0.f;

  if (g == 0) {
    float v = es[d] + edv;
    v = v > 0.f ? v : NEG_SLOPE * v;
    float w = __expf(v);
    float2 raw = *(const float2*)(hL2 + (size_t)d * 32 + ch);
    __half2* p2 = (__half2*)&raw;
    float2 lo = __half22float2(p2[0]);
    float2 hi = __half22float2(p2[1]);
    acc.x = w * lo.x; acc.y = w * lo.y; acc.z = w * hi.x; acc.w = w * hi.y;
    wsum = w;
  }

  int beg = rowbeg[d], end = rowend[d];
#pragma unroll 2
  for (int j = beg + g; j < end; j += 8) {
    int s = col[j];
    float vv = es[s] + edv;
    vv = vv > 0.f ? vv : NEG_SLOPE * vv;
    float w = __expf(vv);
    float2 raw = *(const float2*)(hL2 + (size_t)s * 32 + ch);
    __half2* p2 = (__half2*)&raw;
    float2 lo = __half22float2(p2[0]);
    float2 hi = __half22float2(p2[1]);
    acc.x += w * lo.x; acc.y += w * lo.y; acc.z += w * hi.x; acc.w += w * hi.y;
    wsum += w;
  }

#pragma unroll
  for (int off = 8; off <= 32; off <<= 1) {
    acc.x += __shfl_xor(acc.x, off);
    acc.y += __shfl_xor(acc.y, off);
    acc.z += __shfl_xor(acc.z, off);
    acc.w += __shfl_xor(acc.w, off);
    wsum  += __shfl_xor(wsum, off);
  }

  if (g == 0) {
    float inv = 1.f / (wsum + 1e-16f);
    const float4 bv = *(const float4*)(bias + ch);
    float4 o;
    o.x = acc.x * inv + bv.x;
    o.y = acc.y * inv + bv.y;
    o.z = acc.z * inv + bv.z;
    o.w = acc.w * inv + bv.w;
    *(float4*)(out + (size_t)d * 32 + ch) = o;
  }
}

extern "C" void kernel_launch(void* const* d_in, const int* in_sizes, int n_in,
                              void* d_out, int out_size, void* d_ws, size_t ws_size,
                              hipStream_t stream) {
  const float* x      = (const float*)d_in[0];
  const int*   ei     = (const int*)d_in[1];
  const float* W1     = (const float*)d_in[2];
  const float* a_src1 = (const float*)d_in[3];
  const float* a_dst1 = (const float*)d_in[4];
  const float* b1     = (const float*)d_in[5];
  const float* W2     = (const float*)d_in[6];
  const float* a_src2 = (const float*)d_in[7];
  const float* a_dst2 = (const float*)d_in[8];
  const float* b2     = (const float*)d_in[9];
  float* out = (float*)d_out;

  const int N = in_sizes[0] / 128;
  const int E = in_sizes[1] / 2;
  const int NB = (N + DB - 1) / DB;
  const int* srcv = ei;
  const int* dstv = ei + E;

  char* base = (char*)d_ws;
  size_t off = 0;
  auto carve = [&](size_t bytes) {
    void* p = base + off;
    off += (bytes + 15) & ~(size_t)15;
    return p;
  };
  __half* h1     = (__half*)carve((size_t)N * 64 * 2);
  float*  es1    = (float*)carve((size_t)N * 2 * 4);
  float*  ed1    = (float*)carve((size_t)N * 2 * 4);
  float*  out1   = (float*)carve((size_t)N * 64 * 4);
  __half* hL2    = (__half*)carve((size_t)N * 32 * 2);
  float*  es2    = (float*)carve((size_t)N * 4);
  float*  ed2    = (float*)carve((size_t)N * 4);
  int*    gcur   = (int*)carve((size_t)NB_MAX * 4);
  int*    rowbeg = (int*)carve((size_t)N * 4);
  int*    rowend = (int*)carve((size_t)N * 4);
  int*    col    = (int*)carve((size_t)NB * CAP * 4);
  int*    ebuf   = (int*)carve((size_t)NB * CAP * 4);

  const int pblocks = (E + EPB - 1) / EPB;

  // ---- CSR build ----
  hipMemsetAsync(gcur, 0, (size_t)NB_MAX * sizeof(int), stream);
  k_part<<<pblocks, 256, 0, stream>>>(srcv, dstv, gcur, ebuf, E);
  k_csr<<<NB, 256, 0, stream>>>(gcur, ebuf, rowbeg, rowend, col, N);

  // ---- layer 1 ----
  k_gemm1<<<(N + 63) / 64, 256, 0, stream>>>(x, W1, a_src1, a_dst1, h1, es1, ed1, N);
  k_agg1<<<((size_t)N * 64 + 255) / 256, 256, 0, stream>>>(rowbeg, rowend, col, h1, es1, ed1, b1, out1, N);

  // ---- layer 2 ----
  k_gemm2<<<(N + 127) / 128, 256, 0, stream>>>(out1, W2, a_src2, a_dst2, hL2, es2, ed2, N);
  k_agg2<<<((size_t)N * 64 + 255) / 256, 256, 0, stream>>>(rowbeg, rowend, col, hL2, es2, ed2, b2, out, N);
}

// Round 7
// 213.912 us; speedup vs baseline: 4.4159x; 1.0397x over previous
//
#include <hip/hip_runtime.h>
#include <hip/hip_fp16.h>

#define NEG_SLOPE 0.2f
#define DB 128       // dst nodes per bucket
#define NB_MAX 512   // max buckets (N <= 65536)
#define EPB 4096     // edges per block in partition path
#define CAP 8192     // fixed capacity per bucket segment (mean load ~4092)

// ============ merged: GEMM1+scores1 (blocks [0,G1)) ∥ edge partition (blocks [G1,..)) ============
__global__ __launch_bounds__(256) void k_g1p(
    const float* __restrict__ x, const float* __restrict__ W,
    const float* __restrict__ a_src, const float* __restrict__ a_dst,
    __half* __restrict__ h1, float* __restrict__ es, float* __restrict__ ed, int N,
    const int* __restrict__ srcv, const int* __restrict__ dstv,
    int* __restrict__ gcur, int* __restrict__ ebuf, int E, int G1) {
  __shared__ __align__(16) char smem[65536];
  const int t = threadIdx.x;

  if ((int)blockIdx.x < G1) {
    // ---------------- GEMM1 + fused scores1 ----------------
    float* sXT = (float*)smem;            // [k][row] 128x64, 32 KB
    float* sW  = (float*)(smem + 32768);  // [k][col] 128x64, 32 KB
    const int r0 = blockIdx.x * 64;
    {
      const float4* Wp = (const float4*)W;
      float4* sWp = (float4*)sW;
#pragma unroll
      for (int i = 0; i < 8; ++i) sWp[t + i * 256] = Wp[t + i * 256];
    }
    {
      int r = t & 63;
      int kq = t >> 6;
      int gr = r0 + r;
      bool ok = gr < N;
      const float* xr = x + (size_t)gr * 128;
#pragma unroll
      for (int p = 0; p < 8; ++p) {
        int k = (kq + p * 4) * 4;
        float4 v = ok ? *(const float4*)(xr + k) : make_float4(0.f, 0.f, 0.f, 0.f);
        sXT[(k + 0) * 64 + r] = v.x;
        sXT[(k + 1) * 64 + r] = v.y;
        sXT[(k + 2) * 64 + r] = v.z;
        sXT[(k + 3) * 64 + r] = v.w;
      }
    }
    __syncthreads();

    const int tx = t & 15, ty = t >> 4;
    float4 acc0 = make_float4(0.f, 0.f, 0.f, 0.f);
    float4 acc1 = acc0, acc2 = acc0, acc3 = acc0;
#pragma unroll 8
    for (int k = 0; k < 128; ++k) {
      float4 av = *(const float4*)(sXT + k * 64 + ty * 4);
      float4 bv = *(const float4*)(sW + k * 64 + tx * 4);
      acc0.x += av.x * bv.x; acc0.y += av.x * bv.y; acc0.z += av.x * bv.z; acc0.w += av.x * bv.w;
      acc1.x += av.y * bv.x; acc1.y += av.y * bv.y; acc1.z += av.y * bv.z; acc1.w += av.y * bv.w;
      acc2.x += av.z * bv.x; acc2.y += av.z * bv.y; acc2.z += av.z * bv.z; acc2.w += av.z * bv.w;
      acc3.x += av.w * bv.x; acc3.y += av.w * bv.y; acc3.z += av.w * bv.z; acc3.w += av.w * bv.w;
    }

    float4 accs[4] = {acc0, acc1, acc2, acc3};
#pragma unroll
    for (int i = 0; i < 4; ++i) {
      int gr = r0 + ty * 4 + i;
      if (gr < N) {
        union { __half2 h[2]; float2 f; } u;
        u.h[0] = __float22half2_rn(make_float2(accs[i].x, accs[i].y));
        u.h[1] = __float22half2_rn(make_float2(accs[i].z, accs[i].w));
        *(float2*)(h1 + (size_t)gr * 64 + tx * 4) = u.f;
      }
    }

    float4 asv = *(const float4*)(a_src + tx * 4);
    float4 adv = *(const float4*)(a_dst + tx * 4);
    float esp[4], edp[4];
#pragma unroll
    for (int i = 0; i < 4; ++i) {
      esp[i] = accs[i].x * asv.x + accs[i].y * asv.y + accs[i].z * asv.z + accs[i].w * asv.w;
      edp[i] = accs[i].x * adv.x + accs[i].y * adv.y + accs[i].z * adv.z + accs[i].w * adv.w;
    }
#pragma unroll
    for (int off = 1; off <= 4; off <<= 1) {
#pragma unroll
      for (int i = 0; i < 4; ++i) {
        esp[i] += __shfl_xor(esp[i], off);
        edp[i] += __shfl_xor(edp[i], off);
      }
    }
    if ((tx & 7) == 0) {
      int hh = tx >> 3;
#pragma unroll
      for (int i = 0; i < 4; ++i) {
        int gr = r0 + ty * 4 + i;
        if (gr < N) {
          es[gr * 2 + hh] = esp[i];
          ed[gr * 2 + hh] = edp[i];
        }
      }
    }
  } else {
    // ---------------- edge partition into fixed-cap bucket segments ----------------
    int* sh    = (int*)smem;           // 512 ints
    int* lbase = (int*)(smem + 2048);  // 512 ints
    sh[t] = 0; sh[t + 256] = 0;
    __syncthreads();
    int base = (blockIdx.x - G1) * EPB;
    int dd[16];
#pragma unroll
    for (int i = 0; i < 16; ++i) {
      int e = base + i * 256 + t;
      dd[i] = (e < E) ? dstv[e] : -1;
      if (dd[i] >= 0) atomicAdd(&sh[dd[i] >> 7], 1);
    }
    __syncthreads();
#pragma unroll
    for (int i = 0; i < 2; ++i) {
      int b = t + 256 * i;
      int c = sh[b];
      lbase[b] = c ? (b * CAP + atomicAdd(&gcur[b], c)) : 0;
      sh[b] = 0;  // becomes local cursor
    }
    __syncthreads();
#pragma unroll
    for (int i = 0; i < 16; ++i) {
      if (dd[i] >= 0) {
        int e = base + i * 256 + t;
        int b = dd[i] >> 7;
        int r = atomicAdd(&sh[b], 1);
        ebuf[lbase[b] + r] = srcv[e] | ((dd[i] & 127) << 16);
      }
    }
  }
}

// Phase 2: per-bucket local counting sort -> rowbeg/rowend + col(u16)
__global__ __launch_bounds__(256) void k_csr(const int* __restrict__ gcur,
                                             const int* __restrict__ ebuf,
                                             int* __restrict__ rowbeg,
                                             int* __restrict__ rowend,
                                             unsigned short* __restrict__ col, int N) {
  int b = blockIdx.x;
  int cnt = gcur[b];
  int base = b * CAP;
  int dbase = b * DB;
  __shared__ int dh[DB];
  __shared__ int sc[DB];
  int t = threadIdx.x;
  if (t < DB) dh[t] = 0;
  __syncthreads();
  for (int j = t; j < cnt; j += 256) {
    int p = ebuf[base + j];
    atomicAdd(&dh[p >> 16], 1);
  }
  __syncthreads();
  int v = 0;
  if (t < DB) { v = dh[t]; sc[t] = v; }
  __syncthreads();
  for (int off = 1; off < DB; off <<= 1) {
    int u = 0;
    if (t < DB && t >= off) u = sc[t - off];
    __syncthreads();
    if (t < DB) sc[t] += u;
    __syncthreads();
  }
  if (t < DB) {
    int excl = sc[t] - v;
    int d = dbase + t;
    if (d < N) {
      rowbeg[d] = base + excl;
      rowend[d] = base + excl + v;
    }
    dh[t] = base + excl;
  }
  __syncthreads();
  for (int j = t; j < cnt; j += 256) {
    int p = ebuf[base + j];
    int r = atomicAdd(&dh[p >> 16], 1);
    col[r] = (unsigned short)(p & 0xFFFF);
  }
}

// -------- agg layer 1: one wave per dst; 8 groups x 8 lanes; 8 edges in flight --------
__global__ __launch_bounds__(256) void k_agg1(const int* __restrict__ rowbeg,
                                              const int* __restrict__ rowend,
                                              const unsigned short* __restrict__ col,
                                              const __half* __restrict__ h1,
                                              const float* __restrict__ es,
                                              const float* __restrict__ ed,
                                              const float* __restrict__ bias,
                                              float* __restrict__ out1, int N) {
  int d = (blockIdx.x * blockDim.x + threadIdx.x) >> 6;
  int lane = threadIdx.x & 63;
  if (d >= N) return;
  int g = lane >> 3;   // edge group 0..7
  int q = lane & 7;    // channel octet 0..7
  int ch = q * 8;      // 8 halves per lane
  int hh = q >> 2;     // head: q 0-3 -> 0, 4-7 -> 1
  float edv = ed[d * 2 + hh];

  float a0 = 0.f, a1 = 0.f, a2 = 0.f, a3 = 0.f, a4 = 0.f, a5 = 0.f, a6 = 0.f, a7 = 0.f;
  float wsum = 0.f;

  if (g == 0) {  // self-loop
    float v = es[d * 2 + hh] + edv;
    v = v > 0.f ? v : NEG_SLOPE * v;
    float w = __expf(v);
    float4 raw = *(const float4*)(h1 + (size_t)d * 64 + ch);
    const __half2* p2 = (const __half2*)&raw;
    float2 f0 = __half22float2(p2[0]), f1 = __half22float2(p2[1]);
    float2 f2 = __half22float2(p2[2]), f3 = __half22float2(p2[3]);
    a0 = w * f0.x; a1 = w * f0.y; a2 = w * f1.x; a3 = w * f1.y;
    a4 = w * f2.x; a5 = w * f2.y; a6 = w * f3.x; a7 = w * f3.y;
    wsum = w;
  }

  int beg = rowbeg[d], end = rowend[d];
  for (int j = beg + g; j < end; j += 8) {
    int s = col[j];
    float vv = es[s * 2 + hh] + edv;
    vv = vv > 0.f ? vv : NEG_SLOPE * vv;
    float w = __expf(vv);
    float4 raw = *(const float4*)(h1 + (size_t)s * 64 + ch);
    const __half2* p2 = (const __half2*)&raw;
    float2 f0 = __half22float2(p2[0]), f1 = __half22float2(p2[1]);
    float2 f2 = __half22float2(p2[2]), f3 = __half22float2(p2[3]);
    a0 += w * f0.x; a1 += w * f0.y; a2 += w * f1.x; a3 += w * f1.y;
    a4 += w * f2.x; a5 += w * f2.y; a6 += w * f3.x; a7 += w * f3.y;
    wsum += w;
  }

#pragma unroll
  for (int off = 8; off <= 32; off <<= 1) {
    a0 += __shfl_xor(a0, off); a1 += __shfl_xor(a1, off);
    a2 += __shfl_xor(a2, off); a3 += __shfl_xor(a3, off);
    a4 += __shfl_xor(a4, off); a5 += __shfl_xor(a5, off);
    a6 += __shfl_xor(a6, off); a7 += __shfl_xor(a7, off);
    wsum += __shfl_xor(wsum, off);
  }

  if (g == 0) {
    float inv = 1.f / (wsum + 1e-16f);
    const float4 bv0 = *(const float4*)(bias + ch);
    const float4 bv1 = *(const float4*)(bias + ch + 4);
    float4 o0, o1;
    o0.x = a0 * inv + bv0.x; o0.y = a1 * inv + bv0.y;
    o0.z = a2 * inv + bv0.z; o0.w = a3 * inv + bv0.w;
    o1.x = a4 * inv + bv1.x; o1.y = a5 * inv + bv1.y;
    o1.z = a6 * inv + bv1.z; o1.w = a7 * inv + bv1.w;
    *(float4*)(out1 + (size_t)d * 64 + ch) = o0;
    *(float4*)(out1 + (size_t)d * 64 + ch + 4) = o1;
  }
}

// ======== GEMM2 + fused scores2: hL2(fp16) = relu(out1)@W2 ; es2/ed2 ========
__global__ __launch_bounds__(256) void k_gemm2(const float* __restrict__ out1,
                                               const float* __restrict__ W,
                                               const float* __restrict__ a_src,
                                               const float* __restrict__ a_dst,
                                               __half* __restrict__ hL2,
                                               float* __restrict__ es,
                                               float* __restrict__ ed, int N) {
  __shared__ float sXT[64 * 128];
  __shared__ float sW[64 * 32];
  const int t = threadIdx.x;
  const int r0 = blockIdx.x * 128;

  {
    const float4* Wp = (const float4*)W;
    float4* sWp = (float4*)sW;
#pragma unroll
    for (int i = 0; i < 2; ++i) sWp[t + i * 256] = Wp[t + i * 256];
  }
  {
    int r = t & 127;
    int kq = t >> 7;
    int gr = r0 + r;
    bool ok = gr < N;
    const float* xr = out1 + (size_t)gr * 64;
#pragma unroll
    for (int p = 0; p < 8; ++p) {
      int k = (kq + p * 2) * 4;
      float4 v = ok ? *(const float4*)(xr + k) : make_float4(0.f, 0.f, 0.f, 0.f);
      sXT[(k + 0) * 128 + r] = fmaxf(v.x, 0.f);
      sXT[(k + 1) * 128 + r] = fmaxf(v.y, 0.f);
      sXT[(k + 2) * 128 + r] = fmaxf(v.z, 0.f);
      sXT[(k + 3) * 128 + r] = fmaxf(v.w, 0.f);
    }
  }
  __syncthreads();

  const int tx = t & 7, ty = t >> 3;
  float4 acc0 = make_float4(0.f, 0.f, 0.f, 0.f);
  float4 acc1 = acc0, acc2 = acc0, acc3 = acc0;
#pragma unroll 8
  for (int k = 0; k < 64; ++k) {
    float4 av = *(const float4*)(sXT + k * 128 + ty * 4);
    float4 bv = *(const float4*)(sW + k * 32 + tx * 4);
    acc0.x += av.x * bv.x; acc0.y += av.x * bv.y; acc0.z += av.x * bv.z; acc0.w += av.x * bv.w;
    acc1.x += av.y * bv.x; acc1.y += av.y * bv.y; acc1.z += av.y * bv.z; acc1.w += av.y * bv.w;
    acc2.x += av.z * bv.x; acc2.y += av.z * bv.y; acc2.z += av.z * bv.z; acc2.w += av.z * bv.w;
    acc3.x += av.w * bv.x; acc3.y += av.w * bv.y; acc3.z += av.w * bv.z; acc3.w += av.w * bv.w;
  }

  float4 accs[4] = {acc0, acc1, acc2, acc3};
#pragma unroll
  for (int i = 0; i < 4; ++i) {
    int gr = r0 + ty * 4 + i;
    if (gr < N) {
      union { __half2 h[2]; float2 f; } u;
      u.h[0] = __float22half2_rn(make_float2(accs[i].x, accs[i].y));
      u.h[1] = __float22half2_rn(make_float2(accs[i].z, accs[i].w));
      *(float2*)(hL2 + (size_t)gr * 32 + tx * 4) = u.f;
    }
  }

  float4 asv = *(const float4*)(a_src + tx * 4);
  float4 adv = *(const float4*)(a_dst + tx * 4);
  float esp[4], edp[4];
#pragma unroll
  for (int i = 0; i < 4; ++i) {
    esp[i] = accs[i].x * asv.x + accs[i].y * asv.y + accs[i].z * asv.z + accs[i].w * asv.w;
    edp[i] = accs[i].x * adv.x + accs[i].y * adv.y + accs[i].z * adv.z + accs[i].w * adv.w;
  }
#pragma unroll
  for (int off = 1; off <= 4; off <<= 1) {
#pragma unroll
    for (int i = 0; i < 4; ++i) {
      esp[i] += __shfl_xor(esp[i], off);
      edp[i] += __shfl_xor(edp[i], off);
    }
  }
  if (tx == 0) {
#pragma unroll
    for (int i = 0; i < 4; ++i) {
      int gr = r0 + ty * 4 + i;
      if (gr < N) {
        es[gr] = esp[i];
        ed[gr] = edp[i];
      }
    }
  }
}

// -------- agg layer 2: one wave per dst; 16 groups x 4 lanes; 16 edges in flight --------
__global__ __launch_bounds__(256) void k_agg2(const int* __restrict__ rowbeg,
                                              const int* __restrict__ rowend,
                                              const unsigned short* __restrict__ col,
                                              const __half* __restrict__ hL2,
                                              const float* __restrict__ es,
                                              const float* __restrict__ ed,
                                              const float* __restrict__ bias,
                                              float* __restrict__ out, int N) {
  int d = (blockIdx.x * blockDim.x + threadIdx.x) >> 6;
  int lane = threadIdx.x & 63;
  if (d >= N) return;
  int g = lane >> 2;   // edge group 0..15
  int q = lane & 3;    // channel octet 0..3
  int ch = q * 8;
  float edv = ed[d];

  float a0 = 0.f, a1 = 0.f, a2 = 0.f, a3 = 0.f, a4 = 0.f, a5 = 0.f, a6 = 0.f, a7 = 0.f;
  float wsum = 0.f;

  if (g == 0) {
    float v = es[d] + edv;
    v = v > 0.f ? v : NEG_SLOPE * v;
    float w = __expf(v);
    float4 raw = *(const float4*)(hL2 + (size_t)d * 32 + ch);
    const __half2* p2 = (const __half2*)&raw;
    float2 f0 = __half22float2(p2[0]), f1 = __half22float2(p2[1]);
    float2 f2 = __half22float2(p2[2]), f3 = __half22float2(p2[3]);
    a0 = w * f0.x; a1 = w * f0.y; a2 = w * f1.x; a3 = w * f1.y;
    a4 = w * f2.x; a5 = w * f2.y; a6 = w * f3.x; a7 = w * f3.y;
    wsum = w;
  }

  int beg = rowbeg[d], end = rowend[d];
  for (int j = beg + g; j < end; j += 16) {
    int s = col[j];
    float vv = es[s] + edv;
    vv = vv > 0.f ? vv : NEG_SLOPE * vv;
    float w = __expf(vv);
    float4 raw = *(const float4*)(hL2 + (size_t)s * 32 + ch);
    const __half2* p2 = (const __half2*)&raw;
    float2 f0 = __half22float2(p2[0]), f1 = __half22float2(p2[1]);
    float2 f2 = __half22float2(p2[2]), f3 = __half22float2(p2[3]);
    a0 += w * f0.x; a1 += w * f0.y; a2 += w * f1.x; a3 += w * f1.y;
    a4 += w * f2.x; a5 += w * f2.y; a6 += w * f3.x; a7 += w * f3.y;
    wsum += w;
  }

#pragma unroll
  for (int off = 4; off <= 32; off <<= 1) {
    a0 += __shfl_xor(a0, off); a1 += __shfl_xor(a1, off);
    a2 += __shfl_xor(a2, off); a3 += __shfl_xor(a3, off);
    a4 += __shfl_xor(a4, off); a5 += __shfl_xor(a5, off);
    a6 += __shfl_xor(a6, off); a7 += __shfl_xor(a7, off);
    wsum += __shfl_xor(wsum, off);
  }

  if (g == 0) {
    float inv = 1.f / (wsum + 1e-16f);
    const float4 bv0 = *(const float4*)(bias + ch);
    const float4 bv1 = *(const float4*)(bias + ch + 4);
    float4 o0, o1;
    o0.x = a0 * inv + bv0.x; o0.y = a1 * inv + bv0.y;
    o0.z = a2 * inv + bv0.z; o0.w = a3 * inv + bv0.w;
    o1.x = a4 * inv + bv1.x; o1.y = a5 * inv + bv1.y;
    o1.z = a6 * inv + bv1.z; o1.w = a7 * inv + bv1.w;
    *(float4*)(out + (size_t)d * 32 + ch) = o0;
    *(float4*)(out + (size_t)d * 32 + ch + 4) = o1;
  }
}

extern "C" void kernel_launch(void* const* d_in, const int* in_sizes, int n_in,
                              void* d_out, int out_size, void* d_ws, size_t ws_size,
                              hipStream_t stream) {
  const float* x      = (const float*)d_in[0];
  const int*   ei     = (const int*)d_in[1];
  const float* W1     = (const float*)d_in[2];
  const float* a_src1 = (const float*)d_in[3];
  const float* a_dst1 = (const float*)d_in[4];
  const float* b1     = (const float*)d_in[5];
  const float* W2     = (const float*)d_in[6];
  const float* a_src2 = (const float*)d_in[7];
  const float* a_dst2 = (const float*)d_in[8];
  const float* b2     = (const float*)d_in[9];
  float* out = (float*)d_out;

  const int N = in_sizes[0] / 128;
  const int E = in_sizes[1] / 2;
  const int NB = (N + DB - 1) / DB;
  const int* srcv = ei;
  const int* dstv = ei + E;

  char* base = (char*)d_ws;
  size_t off = 0;
  auto carve = [&](size_t bytes) {
    void* p = base + off;
    off += (bytes + 15) & ~(size_t)15;
    return p;
  };
  __half* h1     = (__half*)carve((size_t)N * 64 * 2);
  float*  es1    = (float*)carve((size_t)N * 2 * 4);
  float*  ed1    = (float*)carve((size_t)N * 2 * 4);
  float*  out1   = (float*)carve((size_t)N * 64 * 4);
  __half* hL2    = (__half*)carve((size_t)N * 32 * 2);
  float*  es2    = (float*)carve((size_t)N * 4);
  float*  ed2    = (float*)carve((size_t)N * 4);
  int*    gcur   = (int*)carve((size_t)NB_MAX * 4);
  int*    rowbeg = (int*)carve((size_t)N * 4);
  int*    rowend = (int*)carve((size_t)N * 4);
  unsigned short* col = (unsigned short*)carve((size_t)NB * CAP * 2);
  int*    ebuf   = (int*)carve((size_t)NB * CAP * 4);

  const int pblocks = (E + EPB - 1) / EPB;
  const int G1 = (N + 63) / 64;

  hipMemsetAsync(gcur, 0, (size_t)NB_MAX * sizeof(int), stream);

  // ---- gemm1+scores1 ∥ edge partition (independent) ----
  k_g1p<<<G1 + pblocks, 256, 0, stream>>>(x, W1, a_src1, a_dst1, h1, es1, ed1, N,
                                          srcv, dstv, gcur, ebuf, E, G1);
  // ---- per-bucket CSR finalize ----
  k_csr<<<NB, 256, 0, stream>>>(gcur, ebuf, rowbeg, rowend, col, N);

  // ---- layer 1 aggregate ----
  k_agg1<<<((size_t)N * 64 + 255) / 256, 256, 0, stream>>>(rowbeg, rowend, col, h1, es1, ed1, b1, out1, N);

  // ---- layer 2 ----
  k_gemm2<<<(N + 127) / 128, 256, 0, stream>>>(out1, W2, a_src2, a_dst2, hL2, es2, ed2, N);
  k_agg2<<<((size_t)N * 64 + 255) / 256, 256, 0, stream>>>(rowbeg, rowend, col, hL2, es2, ed2, b2, out, N);
}